// Round 14
// baseline (508.782 us; speedup 1.0000x reference)
//
#include <hip/hip_runtime.h>
#include <math.h>

#define NA 16384
#define ER 524288
#define EB 32768
#define ET 557056
#define INV_NORM 0.17149858514250882f   // 1/sqrt((ER+EB)/NA) = 1/sqrt(34)
#define SQRT3 1.7320508075688772f
#define RB_STEP (1.5f/9.0f)
#define BINS 512
#define DMAX 2.5f
#define INV_H ((float)BINS / DMAX)
#define T0U (2 * BINS * 128)    // agg0 table: [2][BINS][64][2] uints
#define TLU (2 * BINS * 256)    // layer table: [2][BINS][64][4] uints

typedef unsigned int uint32;
typedef unsigned short ushort16;
typedef float vf4 __attribute__((ext_vector_type(4)));
typedef float vf2 __attribute__((ext_vector_type(2)));
typedef unsigned int vu2 __attribute__((ext_vector_type(2)));

__device__ __forceinline__ float sigmoidf_(float x) { return 1.f / (1.f + __expf(-x)); }

__device__ __forceinline__ ushort16 f2bf(float x) {
  uint32 u = __float_as_uint(x);
  u = u + 0x7FFFu + ((u >> 16) & 1u);
  return (ushort16)(u >> 16);
}
__device__ __forceinline__ uint32 packbf(float hi, float lo) {
  return ((uint32)f2bf(hi) << 16) | (uint32)f2bf(lo);
}
__device__ __forceinline__ float bfhi(uint32 u) { return __uint_as_float(u & 0xFFFF0000u); }
__device__ __forceinline__ float bflo(uint32 u) { return __uint_as_float(u << 16); }

// nontemporal helpers (streaming data must not evict the gather working set)
__device__ __forceinline__ float4 ntl4(const float* p) {
  vf4 v = __builtin_nontemporal_load((const vf4*)p);
  return make_float4(v.x, v.y, v.z, v.w);
}
__device__ __forceinline__ float2 ntl2(const float* p) {
  vf2 v = __builtin_nontemporal_load((const vf2*)p);
  return make_float2(v.x, v.y);
}
__device__ __forceinline__ void nts4(float* p, float a, float b, float c, float d) {
  vf4 v; v.x = a; v.y = b; v.z = c; v.w = d;
  __builtin_nontemporal_store(v, (vf4*)p);
}
__device__ __forceinline__ void nts2(float* p, float a, float b) {
  vf2 v; v.x = a; v.y = b;
  __builtin_nontemporal_store(v, (vf2*)p);
}
__device__ __forceinline__ void ntsu2(uint32* p, uint32 a, uint32 b) {
  vu2 v; v.x = a; v.y = b;
  __builtin_nontemporal_store(v, (vu2*)p);
}
__device__ __forceinline__ void nts1(float* p, float a) {
  __builtin_nontemporal_store(a, p);
}

// ---------------- CSR build ----------------
__global__ void k_hist(const int* __restrict__ rad, const int* __restrict__ bon, int* __restrict__ count) {
  int e = blockIdx.x * 256 + threadIdx.x;
  int d = (e < ER) ? rad[ER + e] : bon[EB + (e - ER)];
  atomicAdd(&count[d], 1);
}

__global__ void k_scan1(const int* __restrict__ count, int* __restrict__ partial) {
  __shared__ int red[256];
  int b = blockIdx.x, t = threadIdx.x;
  red[t] = count[b * 256 + t];
  __syncthreads();
  for (int s = 128; s > 0; s >>= 1) {
    if (t < s) red[t] += red[t + s];
    __syncthreads();
  }
  if (t == 0) partial[b] = red[0];
}

__global__ void k_scan2(int* __restrict__ partial) {
  int run = 0;
  for (int i = 0; i < 64; ++i) { int c = partial[i]; partial[i] = run; run += c; }
}

__global__ void k_scan3(const int* __restrict__ count, const int* __restrict__ partial,
                        int* __restrict__ offsets, int* __restrict__ cursor) {
  __shared__ int sc[256];
  int b = blockIdx.x, t = threadIdx.x;
  int v = count[b * 256 + t];
  sc[t] = v;
  __syncthreads();
  for (int off = 1; off < 256; off <<= 1) {
    int x = (t >= off) ? sc[t - off] : 0;
    __syncthreads();
    sc[t] += x;
    __syncthreads();
  }
  int excl = sc[t] - v + partial[b];
  offsets[b * 256 + t] = excl;
  cursor[b * 256 + t] = excl;
  if (b == 63 && t == 255) offsets[NA] = excl + v;
}

// ---------------- fused: fill+edge-records | embedding ----------------
// record[slot] (32B): {src, Y0, Y1, Y2, frac, qoffL, pad, pad}; agg0 offset = qoffL>>1
__global__ void k_fill_embed(const int* __restrict__ rad, const int* __restrict__ bon,
                             int* __restrict__ cursor, const float* __restrict__ pos,
                             float* __restrict__ rec8,
                             const float* __restrict__ atom_tab, const int* __restrict__ types,
                             const float* __restrict__ ns0_w, const float* __restrict__ cnoise,
                             float* __restrict__ s_feat, ushort16* __restrict__ s_bf) {
  if (blockIdx.x < ET / 256) {
    int e = blockIdx.x * 256 + threadIdx.x;
    int src, dst, v;
    if (e < ER) { src = rad[e]; dst = rad[ER + e]; v = 0; }
    else        { src = bon[e - ER]; dst = bon[EB + e - ER]; v = 1; }
    float dx = pos[src * 3] - pos[dst * 3];
    float dy = pos[src * 3 + 1] - pos[dst * 3 + 1];
    float dz = pos[src * 3 + 2] - pos[dst * 3 + 2];
    float dist = sqrtf(dx * dx + dy * dy + dz * dz + 1e-12f);
    float inv = 1.f / dist;
    float fq = fminf(dist * INV_H, BINS - 1.001f);
    int q = (int)fq;
    float frac = fq - (float)q;
    int qoffL = (v * BINS + q) << 8;
    int slot = atomicAdd(&cursor[dst], 1);
    float* rp = rec8 + (size_t)slot * 8;
    nts4(rp, __int_as_float(src), SQRT3 * dx * inv, SQRT3 * dy * inv, SQRT3 * dz * inv);
    nts2(rp + 4, frac, __int_as_float(qoffL));
  } else {
    int tid = (blockIdx.x - ET / 256) * 256 + threadIdx.x;
    int n = tid >> 6, c = tid & 63;
    float cn = cnoise[0];
    float v = atom_tab[types[n] * 64 + c] * (1.f + cn * ns0_w[c]);
    s_feat[tid] = v;
    s_bf[tid] = f2bf(v);
  }
}

// ---------------- bf16 tables, bond base folded ----------------
__global__ void k_build(const float* __restrict__ We0, const float* __restrict__ We1,
                        const float* __restrict__ We_ss, const float* __restrict__ We_vs,
                        const float* __restrict__ We_sv, const float* __restrict__ We_vv,
                        const float* __restrict__ We_vx, const float* __restrict__ bond_tab,
                        uint32* __restrict__ T0, uint32* __restrict__ TL) {
  int q = blockIdx.x, t = blockIdx.y, v = blockIdx.z, c = threadIdx.x;
  float d0 = q * (DMAX / BINS), d1 = (q + 1) * (DMAX / BINS);
  float rb0[8], rb1[8];
#pragma unroll
  for (int k = 0; k < 8; ++k) {
    float f0 = (d0 - (k + 1) * RB_STEP) * (1.f / RB_STEP);
    float f1 = (d1 - (k + 1) * RB_STEP) * (1.f / RB_STEP);
    rb0[k] = 1.12f * __expf(-f0 * f0);
    rb1[k] = 1.12f * __expf(-f1 * f1);
  }
  if (t == 0) {
    float ba = 0, bb = 0, a0 = 0, a1 = 0, b0 = 0, b1 = 0;
#pragma unroll
    for (int k = 0; k < 8; ++k) {
      float bt = bond_tab[v * 8 + k];
      float av_lo = We0[k * 64 + c], av_hi = We0[(8 + k) * 64 + c];
      float bv_lo = We1[k * 64 + c], bv_hi = We1[(8 + k) * 64 + c];
      ba += bt * av_lo; bb += bt * bv_lo;
      a0 += rb0[k] * av_hi; a1 += rb1[k] * av_hi;
      b0 += rb0[k] * bv_hi; b1 += rb1[k] * bv_hi;
    }
    uint32* o = T0 + (((size_t)v * BINS + q) << 7) + c * 2;
    o[0] = packbf(ba + a0, a1 - a0);
    o[1] = packbf(bb + b0, b1 - b0);
  } else {
    int l = t - 1;
    const float* Wss = We_ss + l * 1024;
    const float* Wsv = We_sv + l * 1024;
    const float* WA = (c < 32) ? (We_vs + l * 512) : (We_vx + l * 512);
    const float* WB = (c < 32) ? (We_vv + l * 512) : nullptr;
    int cu = c & 31;
    float sa = 0, sb = 0, s0 = 0, s1 = 0, t0 = 0, t1 = 0;
    float ua = 0, ub = 0, u0 = 0, u1 = 0, w0 = 0, w1 = 0;
#pragma unroll
    for (int k = 0; k < 8; ++k) {
      float bt = bond_tab[v * 8 + k];
      float ss_lo = Wss[k * 64 + c], ss_hi = Wss[(8 + k) * 64 + c];
      float sv_lo = Wsv[k * 64 + c], sv_hi = Wsv[(8 + k) * 64 + c];
      sa += bt * ss_lo; sb += bt * sv_lo;
      s0 += rb0[k] * ss_hi; s1 += rb1[k] * ss_hi;
      t0 += rb0[k] * sv_hi; t1 += rb1[k] * sv_hi;
      float a_lo = WA[k * 32 + cu], a_hi = WA[(8 + k) * 32 + cu];
      ua += bt * a_lo;
      u0 += rb0[k] * a_hi; u1 += rb1[k] * a_hi;
      if (WB) {
        float b_lo = WB[k * 32 + cu], b_hi = WB[(8 + k) * 32 + cu];
        ub += bt * b_lo;
        w0 += rb0[k] * b_hi; w1 += rb1[k] * b_hi;
      }
    }
    uint32* o = TL + (size_t)l * TLU + (((size_t)v * BINS + q) << 8) + c * 4;
    o[0] = packbf(sa + s0, s1 - s0);
    o[1] = packbf(sb + t0, t1 - t0);
    o[2] = packbf(ua + u0, u1 - u0);
    o[3] = WB ? packbf(ub + w0, w1 - w0) : 0u;
  }
}

// ---------------- initial aggregation (3-stage pipeline, nt rec, bf16 a_v) ----------------
// a_v layout: [n][64] uint2 (bf16 x|y, z|0)
__global__ __launch_bounds__(256, 8) void k_agg0(
    const int* __restrict__ offsets, const float* __restrict__ rec8,
    const uint32* __restrict__ T0, const ushort16* __restrict__ s_bf,
    float* __restrict__ a_s, uint32* __restrict__ a_v) {
  int lane = threadIdx.x & 63;
  int n = blockIdx.x * 4 + (threadIdx.x >> 6);
  float acc = 0, a0 = 0, a1 = 0, a2 = 0;
  int beg = __builtin_amdgcn_readfirstlane(offsets[n]);
  int end = __builtin_amdgcn_readfirstlane(offsets[n + 1]);
  if (beg < end) {
    int last = end - 1;
    int e1 = (beg + 1 < end) ? beg + 1 : last;
    int e2 = (beg + 2 < end) ? beg + 2 : last;
    const float* p0 = rec8 + (size_t)beg * 8;
    const float* p1 = rec8 + (size_t)e1 * 8;
    const float* p2 = rec8 + (size_t)e2 * 8;
    float4 rA0 = ntl4(p0); float2 rB0 = ntl2(p0 + 4);
    float4 rA1 = ntl4(p1); float2 rB1 = ntl2(p1 + 4);
    float4 rA2 = ntl4(p2); float2 rB2 = ntl2(p2 + 4);
    uint2 t0 = *(const uint2*)(T0 + (__float_as_int(rB0.y) >> 1) + (lane << 1));
    ushort16 s0 = s_bf[((size_t)__float_as_int(rA0.x) << 6) + lane];
    uint2 t1 = *(const uint2*)(T0 + (__float_as_int(rB1.y) >> 1) + (lane << 1));
    ushort16 s1 = s_bf[((size_t)__float_as_int(rA1.x) << 6) + lane];
#pragma unroll 3
    for (int idx = beg; idx < end; ++idx) {
      uint2 t2 = *(const uint2*)(T0 + (__float_as_int(rB2.y) >> 1) + (lane << 1));
      ushort16 s2 = s_bf[((size_t)__float_as_int(rA2.x) << 6) + lane];
      int e3 = (idx + 3 < end) ? idx + 3 : last;
      const float* p3 = rec8 + (size_t)e3 * 8;
      float4 rA3 = ntl4(p3); float2 rB3 = ntl2(p3 + 4);
      float frac = rB0.x;
      float w0 = fmaf(frac, bflo(t0.x), bfhi(t0.x));
      float w1 = fmaf(frac, bflo(t0.y), bfhi(t0.y));
      float sv = __uint_as_float((uint32)s0 << 16);
      acc += w0 * sv;
      float t = w1 * sv;
      a0 += t * rA0.y; a1 += t * rA0.z; a2 += t * rA0.w;
      rA0 = rA1; rB0 = rB1; rA1 = rA2; rB1 = rB2; rA2 = rA3; rB2 = rB3;
      t0 = t1; s0 = s1; t1 = t2; s1 = s2;
    }
  }
  nts1(a_s + n * 64 + lane, acc * INV_NORM);
  ntsu2(a_v + ((size_t)n << 7) + (lane << 1),
        packbf(a0 * INV_NORM, a1 * INV_NORM), packbf(a2 * INV_NORM, 0.f));
}

// ---------------- layer aggregation (3-stage pipeline, nt rec, bf16 a_v) ----------------
// a_v layout: [n][128] uint2
__global__ __launch_bounds__(256, 8) void k_agg_layer(
    const float* __restrict__ cnoise, const float* __restrict__ nsw,
    const int* __restrict__ offsets, const float* __restrict__ rec8,
    const uint32* __restrict__ TL, const ushort16* __restrict__ sh_bf,
    const uint32* __restrict__ vh_bf,
    float* __restrict__ a_s, uint32* __restrict__ a_v) {
  int lane = threadIdx.x & 63;
  int n = blockIdx.x * 4 + (threadIdx.x >> 6);
  int vc = lane & 31;
  bool low = lane < 32;
  float cn = cnoise[0];
  float scale_s = 1.f + cn * nsw[lane];
  float scale_v = 1.f + cn * nsw[64 + vc];

  float ms = 0;
  float av0 = 0, av1 = 0, av2 = 0;
  float ms2 = 0;
  float b0 = 0, b1 = 0, b2 = 0;
  int beg = __builtin_amdgcn_readfirstlane(offsets[n]);
  int end = __builtin_amdgcn_readfirstlane(offsets[n + 1]);
  if (beg < end) {
    int last = end - 1;
    int e1 = (beg + 1 < end) ? beg + 1 : last;
    int e2 = (beg + 2 < end) ? beg + 2 : last;
    const float* p0 = rec8 + (size_t)beg * 8;
    const float* p1 = rec8 + (size_t)e1 * 8;
    const float* p2 = rec8 + (size_t)e2 * 8;
    float4 rA0 = ntl4(p0); float2 rB0 = ntl2(p0 + 4);
    float4 rA1 = ntl4(p1); float2 rB1 = ntl2(p1 + 4);
    float4 rA2 = ntl4(p2); float2 rB2 = ntl2(p2 + 4);
    uint4 t0 = *(const uint4*)(TL + __float_as_int(rB0.y) + (lane << 2));
    ushort16 s0 = sh_bf[((size_t)__float_as_int(rA0.x) << 6) + lane];
    uint2 v0 = *(const uint2*)(vh_bf + ((size_t)__float_as_int(rA0.x) << 6) + (vc << 1));
    uint4 t1 = *(const uint4*)(TL + __float_as_int(rB1.y) + (lane << 2));
    ushort16 s1 = sh_bf[((size_t)__float_as_int(rA1.x) << 6) + lane];
    uint2 v1 = *(const uint2*)(vh_bf + ((size_t)__float_as_int(rA1.x) << 6) + (vc << 1));
#pragma unroll 3
    for (int idx = beg; idx < end; ++idx) {
      uint4 t2 = *(const uint4*)(TL + __float_as_int(rB2.y) + (lane << 2));
      ushort16 s2 = sh_bf[((size_t)__float_as_int(rA2.x) << 6) + lane];
      uint2 v2 = *(const uint2*)(vh_bf + ((size_t)__float_as_int(rA2.x) << 6) + (vc << 1));
      int e3 = (idx + 3 < end) ? idx + 3 : last;
      const float* p3 = rec8 + (size_t)e3 * 8;
      float4 rA3 = ntl4(p3); float2 rB3 = ntl2(p3 + 4);
      float frac = rB0.x;
      float y0 = rA0.y, y1 = rA0.z, y2 = rA0.w;
      float wS  = fmaf(frac, bflo(t0.x), bfhi(t0.x));
      float wSV = fmaf(frac, bflo(t0.y), bfhi(t0.y));
      float wA  = fmaf(frac, bflo(t0.z), bfhi(t0.z));
      float wB  = fmaf(frac, bflo(t0.w), bfhi(t0.w));
      float ss = __uint_as_float((uint32)s0 << 16);
      float vx = bfhi(v0.x), vy = bflo(v0.x), vz = bfhi(v0.y);
      ms += wS * ss;
      float t = wSV * ss;
      av0 += t * y0; av1 += t * y1; av2 += t * y2;
      float vdot = vx * y0 + vy * y1 + vz * y2;
      ms2 += wA * vdot;  // garbage on high lanes, never written
      float cx = vy * y2 - vz * y1;
      float cy = vz * y0 - vx * y2;
      float cz = vx * y1 - vy * y0;
      float m0 = low ? vx : cx;
      float m1 = low ? vy : cy;
      float m2 = low ? vz : cz;
      float wM = low ? wB : wA;
      b0 += wM * m0; b1 += wM * m1; b2 += wM * m2;
      rA0 = rA1; rB0 = rB1; rA1 = rA2; rB1 = rB2; rA2 = rA3; rB2 = rB3;
      t0 = t1; s0 = s1; v0 = v1; t1 = t2; s1 = s2; v1 = v2;
    }
  }
  float fs = scale_s * INV_NORM;
  float fv = scale_v * INV_NORM;
  nts1(a_s + n * 96 + lane, ms * fs);
  uint32* avn = a_v + ((size_t)n << 8);
  ntsu2(avn + (lane << 1), packbf(av0 * fs, av1 * fs), packbf(av2 * fs, 0.f));
  if (low) {
    nts1(a_s + n * 96 + 64 + vc, ms2 * fv);
    ntsu2(avn + ((64 + vc) << 1), packbf(b0 * fv, b1 * fv), packbf(b2 * fv, 0.f));
  } else {
    ntsu2(avn + ((96 + vc) << 1), packbf(b0 * fv, b1 * fv), packbf(b2 * fv, 0.f));
  }
}

// ---------------- merged init projections (LDS-staged) ----------------
__global__ __launch_bounds__(256, 4) void k_init(
    const float* __restrict__ a_s, const float* __restrict__ s_feat,
    const float* __restrict__ Ws0, const float* __restrict__ Wself0,
    const uint32* __restrict__ a_v, const float* __restrict__ Wv0,
    float* __restrict__ sh, ushort16* __restrict__ sh_bf,
    float* __restrict__ vh, uint32* __restrict__ vh_bf) {
  __shared__ float SM[9216];
  int tid = threadIdx.x;
  if (blockIdx.x < NA / 8) {
    float* W1 = SM;           // 4096
    float* W2 = SM + 4096;    // 4096
    float* La = SM + 8192;    // 512
    float* Lf = SM + 8704;    // 512
    for (int i = tid; i < 1024; i += 256) {
      ((float4*)W1)[i] = ((const float4*)Ws0)[i];
      ((float4*)W2)[i] = ((const float4*)Wself0)[i];
    }
    int base = blockIdx.x * 8;
    for (int i = tid; i < 512; i += 256) {
      La[i] = a_s[(size_t)base * 64 + i];
      Lf[i] = s_feat[(size_t)base * 64 + i];
    }
    __syncthreads();
    int d = tid & 63, g = tid >> 6;
    int n0 = base + g * 2;
    const float* A0 = La + g * 128;
    const float* A1 = A0 + 64;
    const float* F0 = Lf + g * 128;
    const float* F1 = F0 + 64;
    float a0 = 0, a1 = 0;
#pragma unroll 8
    for (int c = 0; c < 64; ++c) {
      float w1 = W1[c * 64 + d], w2 = W2[c * 64 + d];
      a0 += A0[c] * w1 + F0[c] * w2;
      a1 += A1[c] * w1 + F1[c] * w2;
    }
    sh[(size_t)n0 * 64 + d] = a0;
    sh[(size_t)(n0 + 1) * 64 + d] = a1;
    sh_bf[(size_t)n0 * 64 + d] = f2bf(a0);
    sh_bf[(size_t)(n0 + 1) * 64 + d] = f2bf(a1);
  } else {
    float* W = SM;  // 2048
    for (int i = tid; i < 512; i += 256) ((float4*)W)[i] = ((const float4*)Wv0)[i];
    __syncthreads();
    int d = tid & 31, g = tid >> 5;
    int n = (blockIdx.x - NA / 8) * 8 + g;
    const uint2* av = (const uint2*)a_v + ((size_t)n << 6);
    float x = 0, y = 0, z = 0;
#pragma unroll 4
    for (int c = 0; c < 64; ++c) {
      uint2 a = av[c];
      float w = W[c * 32 + d];
      x += bfhi(a.x) * w; y += bflo(a.x) * w; z += bfhi(a.y) * w;
    }
    *(float4*)(vh + ((size_t)n << 7) + (d << 2)) = make_float4(x, y, z, 0.f);
    *(uint2*)(vh_bf + ((size_t)n << 6) + (d << 1)) = make_uint2(packbf(x, y), packbf(z, 0.f));
  }
}

// ---------------- merged mix/self/skip (LDS-staged) ----------------
__global__ __launch_bounds__(256, 4) void k_mix(
    const float* __restrict__ a_s, const float* __restrict__ sh_in,
    const float* __restrict__ Wmix_s, const float* __restrict__ Wself_s,
    const uint32* __restrict__ a_v, const float* __restrict__ vh_in,
    const float* __restrict__ Wmix_v, const float* __restrict__ Wself_v,
    const float* __restrict__ nsw, const float* __restrict__ skw,
    const float* __restrict__ skb, const float* __restrict__ cnoise,
    float* __restrict__ sh_out, ushort16* __restrict__ sh_bf_out,
    float* __restrict__ vh_out, uint32* __restrict__ vh_bf_out) {
  __shared__ float SM[11008];
  int tid = threadIdx.x;
  float cn = cnoise[0];
  if (blockIdx.x < NA / 8) {
    float* Wm = SM;            // 6144
    float* Wsf = SM + 6144;    // 4096
    float* La = SM + 10240;    // 768
    for (int i = tid; i < 96 * 16; i += 256) ((float4*)Wm)[i] = ((const float4*)Wmix_s)[i];
    for (int i = tid; i < 64 * 16; i += 256) {
      float4 wv = ((const float4*)Wself_s)[i];
      int c = i >> 4;
      float sc = 1.f + cn * nsw[c];
      wv.x *= sc; wv.y *= sc; wv.z *= sc; wv.w *= sc;
      ((float4*)Wsf)[i] = wv;
    }
    int base = blockIdx.x * 8;
    for (int i = tid; i < 8 * 96; i += 256) La[i] = a_s[(size_t)base * 96 + i];
    __syncthreads();
    int d = tid & 63, g = tid >> 6;
    int n0 = base + g * 2;
    const float* A0 = La + (g * 2) * 96;
    const float* A1 = A0 + 96;
    const float* s0p = sh_in + (size_t)n0 * 64;
    const float* s1p = s0p + 64;
    float acc0 = 0, acc1 = 0;
#pragma unroll 8
    for (int c = 0; c < 96; ++c) {
      float w = Wm[c * 64 + d];
      acc0 += A0[c] * w;
      acc1 += A1[c] * w;
    }
#pragma unroll 8
    for (int c = 0; c < 64; ++c) {
      float w = Wsf[c * 64 + d];
      acc0 += s0p[c] * w;
      acc1 += s1p[c] * w;
    }
    float g1 = sigmoidf_(skb[d] + cn * skw[d]);
    float g2 = sigmoidf_(skb[64 + d] + cn * skw[64 + d]);
    float o0 = g1 * s0p[d] + g2 * acc0;
    float o1 = g1 * s1p[d] + g2 * acc1;
    sh_out[(size_t)n0 * 64 + d] = o0;
    sh_out[(size_t)(n0 + 1) * 64 + d] = o1;
    sh_bf_out[(size_t)n0 * 64 + d] = f2bf(o0);
    sh_bf_out[(size_t)(n0 + 1) * 64 + d] = f2bf(o1);
  } else {
    float* Wm = SM;            // 4096
    float* Wsf = SM + 4096;    // 1024
    for (int i = tid; i < 128 * 8; i += 256) ((float4*)Wm)[i] = ((const float4*)Wmix_v)[i];
    for (int i = tid; i < 32 * 8; i += 256) {
      float4 wv = ((const float4*)Wself_v)[i];
      int c = i >> 3;
      float sc = 1.f + cn * nsw[64 + c];
      wv.x *= sc; wv.y *= sc; wv.z *= sc; wv.w *= sc;
      ((float4*)Wsf)[i] = wv;
    }
    __syncthreads();
    int d = tid & 31, g = tid >> 5;
    int n = (blockIdx.x - NA / 8) * 8 + g;
    const uint2* av = (const uint2*)a_v + ((size_t)n << 7);
    const float4* vr = (const float4*)(vh_in + ((size_t)n << 7));
    float x = 0, y = 0, z = 0;
#pragma unroll 4
    for (int c = 0; c < 128; ++c) {
      uint2 a = av[c];
      float w = Wm[c * 32 + d];
      x += bfhi(a.x) * w; y += bflo(a.x) * w; z += bfhi(a.y) * w;
    }
#pragma unroll 4
    for (int c = 0; c < 32; ++c) {
      float4 vv = vr[c];
      float w = Wsf[c * 32 + d];
      x += vv.x * w; y += vv.y * w; z += vv.z * w;
    }
    float g3 = sigmoidf_(skb[128 + d] + cn * skw[128 + d]);
    float g4 = sigmoidf_(skb[160 + d] + cn * skw[160 + d]);
    float4 vi = vr[d];
    float ox = g3 * vi.x + g4 * x;
    float oy = g3 * vi.y + g4 * y;
    float oz = g3 * vi.z + g4 * z;
    *(float4*)(vh_out + ((size_t)n << 7) + (d << 2)) = make_float4(ox, oy, oz, 0.f);
    *(uint2*)(vh_bf_out + ((size_t)n << 6) + (d << 1)) = make_uint2(packbf(ox, oy), packbf(oz, 0.f));
  }
}

// ---------------- output ----------------
__global__ void k_out(const float* __restrict__ vh, const float* __restrict__ w_out,
                      const float* __restrict__ gain, float* __restrict__ out) {
  int tid = blockIdx.x * 256 + threadIdx.x;  // < NA*3
  int n = tid / 3, i = tid - n * 3;
  float acc = 0;
  for (int c = 0; c < 32; ++c) acc += vh[((size_t)n << 7) + c * 4 + i] * w_out[c];
  out[tid] = acc * gain[0];
}

extern "C" void kernel_launch(void* const* d_in, const int* in_sizes, int n_in,
                              void* d_out, int out_size, void* d_ws, size_t ws_size,
                              hipStream_t stream) {
  (void)in_sizes; (void)n_in; (void)out_size; (void)ws_size;
  const float* pos     = (const float*)d_in[0];
  const float* cn      = (const float*)d_in[1];
  const int*   types   = (const int*)d_in[2];
  const int*   rad     = (const int*)d_in[3];
  const int*   bon     = (const int*)d_in[4];
  const float* atom_tab= (const float*)d_in[5];
  const float* bond_tab= (const float*)d_in[6];
  const float* ns0_w   = (const float*)d_in[7];
  const float* We0     = (const float*)d_in[8];
  const float* We1     = (const float*)d_in[9];
  const float* Wself0  = (const float*)d_in[10];
  const float* Ws0     = (const float*)d_in[11];
  const float* Wv0     = (const float*)d_in[12];
  const float* ns_w    = (const float*)d_in[13];
  const float* We_ss   = (const float*)d_in[14];
  const float* We_vs   = (const float*)d_in[15];
  const float* We_sv   = (const float*)d_in[16];
  const float* We_vv   = (const float*)d_in[17];
  const float* We_vx   = (const float*)d_in[18];
  const float* Wmix_s  = (const float*)d_in[19];
  const float* Wmix_v  = (const float*)d_in[20];
  const float* Wself_s = (const float*)d_in[21];
  const float* Wself_v = (const float*)d_in[22];
  const float* skip_w  = (const float*)d_in[23];
  const float* skip_b  = (const float*)d_in[24];
  const float* w_out   = (const float*)d_in[25];
  const float* gain    = (const float*)d_in[26];

  char* ws = (char*)d_ws;
  size_t o = 0;
  auto alloc = [&](size_t bytes) -> void* {
    void* p = ws + o;
    o += (bytes + 255) & ~(size_t)255;
    return p;
  };
  float* s_feat  = (float*)alloc((size_t)NA * 64 * 4);
  ushort16* s_bf = (ushort16*)alloc((size_t)NA * 64 * 2);
  float* a_s     = (float*)alloc((size_t)NA * 96 * 4);
  uint32* a_v    = (uint32*)alloc((size_t)NA * 256 * 4);  // [n][128] uint2; agg0 uses [n][64] uint2
  float* sh0     = (float*)alloc((size_t)NA * 64 * 4);
  float* sh1     = (float*)alloc((size_t)NA * 64 * 4);
  ushort16* shbf0= (ushort16*)alloc((size_t)NA * 64 * 2);
  ushort16* shbf1= (ushort16*)alloc((size_t)NA * 64 * 2);
  float* vh0     = (float*)alloc((size_t)NA * 128 * 4);  // [n][32][4]
  float* vh1     = (float*)alloc((size_t)NA * 128 * 4);
  uint32* vhbf0  = (uint32*)alloc((size_t)NA * 64 * 4);  // [n][32][2] uints
  uint32* vhbf1  = (uint32*)alloc((size_t)NA * 64 * 4);
  int* count     = (int*)alloc((size_t)NA * 4);
  int* partial   = (int*)alloc((size_t)64 * 4);
  int* offsets   = (int*)alloc((size_t)(NA + 1) * 4);
  int* cursor    = (int*)alloc((size_t)NA * 4);
  float* rec8    = (float*)alloc((size_t)ET * 32);
  uint32* T0     = (uint32*)alloc((size_t)T0U * 4);
  uint32* TL     = (uint32*)alloc((size_t)2 * TLU * 4);
  float* shb[2]  = {sh0, sh1};
  ushort16* shbf[2] = {shbf0, shbf1};
  float* vhb[2]  = {vh0, vh1};
  uint32* vhbf[2]= {vhbf0, vhbf1};

  // CSR build + tables
  hipMemsetAsync(count, 0, (size_t)NA * 4, stream);
  k_hist<<<ET / 256, 256, 0, stream>>>(rad, bon, count);
  k_scan1<<<64, 256, 0, stream>>>(count, partial);
  k_scan2<<<1, 1, 0, stream>>>(partial);
  k_scan3<<<64, 256, 0, stream>>>(count, partial, offsets, cursor);
  k_fill_embed<<<ET / 256 + NA * 64 / 256, 256, 0, stream>>>(
      rad, bon, cursor, pos, rec8, atom_tab, types, ns0_w, cn, s_feat, s_bf);
  k_build<<<dim3(BINS, 3, 2), 64, 0, stream>>>(We0, We1, We_ss, We_vs, We_sv, We_vv, We_vx,
                                               bond_tab, T0, TL);

  k_agg0<<<NA / 4, 256, 0, stream>>>(offsets, rec8, T0, s_bf, a_s, a_v);
  k_init<<<NA / 4, 256, 0, stream>>>(a_s, s_feat, Ws0, Wself0, a_v, Wv0,
                                     shb[0], shbf[0], vhb[0], vhbf[0]);

  for (int l = 0; l < 2; ++l) {
    int bin = l & 1, bout = 1 - bin;
    k_agg_layer<<<NA / 4, 256, 0, stream>>>(
        cn, ns_w + l * 96, offsets, rec8, TL + (size_t)l * TLU, shbf[bin], vhbf[bin], a_s, a_v);
    k_mix<<<NA / 4, 256, 0, stream>>>(
        a_s, shb[bin], Wmix_s + l * 96 * 64, Wself_s + l * 64 * 64,
        a_v, vhb[bin], Wmix_v + l * 128 * 32, Wself_v + l * 32 * 32,
        ns_w + l * 96, skip_w + l * 192, skip_b + l * 192, cn,
        shb[bout], shbf[bout], vhb[bout], vhbf[bout]);
  }
  k_out<<<NA * 3 / 256, 256, 0, stream>>>(vhb[0], w_out, gain, (float*)d_out);
}

// Round 15
// 503.178 us; speedup vs baseline: 1.0111x; 1.0111x over previous
//
#include <hip/hip_runtime.h>
#include <math.h>

#define NA 16384
#define ER 524288
#define EB 32768
#define ET 557056
#define INV_NORM 0.17149858514250882f   // 1/sqrt((ER+EB)/NA) = 1/sqrt(34)
#define SQRT3 1.7320508075688772f
#define RB_STEP (1.5f/9.0f)
#define BINS 512
#define DMAX 2.5f
#define INV_H ((float)BINS / DMAX)
#define T0U (2 * BINS * 128)    // agg0 table: [2][BINS][64][2] uints
#define TLU (2 * BINS * 256)    // layer table: [2][BINS][64][4] uints

typedef unsigned int uint32;
typedef unsigned short ushort16;
typedef float vf4 __attribute__((ext_vector_type(4)));
typedef float vf2 __attribute__((ext_vector_type(2)));
typedef unsigned int vu2 __attribute__((ext_vector_type(2)));

__device__ __forceinline__ float sigmoidf_(float x) { return 1.f / (1.f + __expf(-x)); }

__device__ __forceinline__ ushort16 f2bf(float x) {
  uint32 u = __float_as_uint(x);
  u = u + 0x7FFFu + ((u >> 16) & 1u);
  return (ushort16)(u >> 16);
}
__device__ __forceinline__ uint32 packbf(float hi, float lo) {
  return ((uint32)f2bf(hi) << 16) | (uint32)f2bf(lo);
}
__device__ __forceinline__ float bfhi(uint32 u) { return __uint_as_float(u & 0xFFFF0000u); }
__device__ __forceinline__ float bflo(uint32 u) { return __uint_as_float(u << 16); }

// nontemporal helpers (streaming data must not evict the gather working set)
__device__ __forceinline__ float4 ntl4(const float* p) {
  vf4 v = __builtin_nontemporal_load((const vf4*)p);
  return make_float4(v.x, v.y, v.z, v.w);
}
__device__ __forceinline__ float2 ntl2(const float* p) {
  vf2 v = __builtin_nontemporal_load((const vf2*)p);
  return make_float2(v.x, v.y);
}
__device__ __forceinline__ void nts4(float* p, float a, float b, float c, float d) {
  vf4 v; v.x = a; v.y = b; v.z = c; v.w = d;
  __builtin_nontemporal_store(v, (vf4*)p);
}
__device__ __forceinline__ void nts2(float* p, float a, float b) {
  vf2 v; v.x = a; v.y = b;
  __builtin_nontemporal_store(v, (vf2*)p);
}
__device__ __forceinline__ void ntsu2(uint32* p, uint32 a, uint32 b) {
  vu2 v; v.x = a; v.y = b;
  __builtin_nontemporal_store(v, (vu2*)p);
}
__device__ __forceinline__ void nts1(float* p, float a) {
  __builtin_nontemporal_store(a, p);
}

// ---------------- CSR build ----------------
__global__ void k_hist(const int* __restrict__ rad, const int* __restrict__ bon, int* __restrict__ count) {
  int e = blockIdx.x * 256 + threadIdx.x;
  int d = (e < ER) ? rad[ER + e] : bon[EB + (e - ER)];
  atomicAdd(&count[d], 1);
}

__global__ void k_scan1(const int* __restrict__ count, int* __restrict__ partial) {
  __shared__ int red[256];
  int b = blockIdx.x, t = threadIdx.x;
  red[t] = count[b * 256 + t];
  __syncthreads();
  for (int s = 128; s > 0; s >>= 1) {
    if (t < s) red[t] += red[t + s];
    __syncthreads();
  }
  if (t == 0) partial[b] = red[0];
}

__global__ void k_scan2(int* __restrict__ partial) {
  int run = 0;
  for (int i = 0; i < 64; ++i) { int c = partial[i]; partial[i] = run; run += c; }
}

__global__ void k_scan3(const int* __restrict__ count, const int* __restrict__ partial,
                        int* __restrict__ offsets, int* __restrict__ cursor) {
  __shared__ int sc[256];
  int b = blockIdx.x, t = threadIdx.x;
  int v = count[b * 256 + t];
  sc[t] = v;
  __syncthreads();
  for (int off = 1; off < 256; off <<= 1) {
    int x = (t >= off) ? sc[t - off] : 0;
    __syncthreads();
    sc[t] += x;
    __syncthreads();
  }
  int excl = sc[t] - v + partial[b];
  offsets[b * 256 + t] = excl;
  cursor[b * 256 + t] = excl;
  if (b == 63 && t == 255) offsets[NA] = excl + v;
}

// ---------------- fused: fill+edge-records | embedding ----------------
// record[slot] (32B): {src, Y0, Y1, Y2, frac, qoffL, pad, pad}; agg0 offset = qoffL>>1
__global__ void k_fill_embed(const int* __restrict__ rad, const int* __restrict__ bon,
                             int* __restrict__ cursor, const float* __restrict__ pos,
                             float* __restrict__ rec8,
                             const float* __restrict__ atom_tab, const int* __restrict__ types,
                             const float* __restrict__ ns0_w, const float* __restrict__ cnoise,
                             float* __restrict__ s_feat, ushort16* __restrict__ s_bf) {
  if (blockIdx.x < ET / 256) {
    int e = blockIdx.x * 256 + threadIdx.x;
    int src, dst, v;
    if (e < ER) { src = rad[e]; dst = rad[ER + e]; v = 0; }
    else        { src = bon[e - ER]; dst = bon[EB + e - ER]; v = 1; }
    float dx = pos[src * 3] - pos[dst * 3];
    float dy = pos[src * 3 + 1] - pos[dst * 3 + 1];
    float dz = pos[src * 3 + 2] - pos[dst * 3 + 2];
    float dist = sqrtf(dx * dx + dy * dy + dz * dz + 1e-12f);
    float inv = 1.f / dist;
    float fq = fminf(dist * INV_H, BINS - 1.001f);
    int q = (int)fq;
    float frac = fq - (float)q;
    int qoffL = (v * BINS + q) << 8;
    int slot = atomicAdd(&cursor[dst], 1);
    float* rp = rec8 + (size_t)slot * 8;
    nts4(rp, __int_as_float(src), SQRT3 * dx * inv, SQRT3 * dy * inv, SQRT3 * dz * inv);
    nts2(rp + 4, frac, __int_as_float(qoffL));
  } else {
    int tid = (blockIdx.x - ET / 256) * 256 + threadIdx.x;
    int n = tid >> 6, c = tid & 63;
    float cn = cnoise[0];
    float v = atom_tab[types[n] * 64 + c] * (1.f + cn * ns0_w[c]);
    s_feat[tid] = v;
    s_bf[tid] = f2bf(v);
  }
}

// ---------------- bf16 tables, bond base folded ----------------
__global__ void k_build(const float* __restrict__ We0, const float* __restrict__ We1,
                        const float* __restrict__ We_ss, const float* __restrict__ We_vs,
                        const float* __restrict__ We_sv, const float* __restrict__ We_vv,
                        const float* __restrict__ We_vx, const float* __restrict__ bond_tab,
                        uint32* __restrict__ T0, uint32* __restrict__ TL) {
  int q = blockIdx.x, t = blockIdx.y, v = blockIdx.z, c = threadIdx.x;
  float d0 = q * (DMAX / BINS), d1 = (q + 1) * (DMAX / BINS);
  float rb0[8], rb1[8];
#pragma unroll
  for (int k = 0; k < 8; ++k) {
    float f0 = (d0 - (k + 1) * RB_STEP) * (1.f / RB_STEP);
    float f1 = (d1 - (k + 1) * RB_STEP) * (1.f / RB_STEP);
    rb0[k] = 1.12f * __expf(-f0 * f0);
    rb1[k] = 1.12f * __expf(-f1 * f1);
  }
  if (t == 0) {
    float ba = 0, bb = 0, a0 = 0, a1 = 0, b0 = 0, b1 = 0;
#pragma unroll
    for (int k = 0; k < 8; ++k) {
      float bt = bond_tab[v * 8 + k];
      float av_lo = We0[k * 64 + c], av_hi = We0[(8 + k) * 64 + c];
      float bv_lo = We1[k * 64 + c], bv_hi = We1[(8 + k) * 64 + c];
      ba += bt * av_lo; bb += bt * bv_lo;
      a0 += rb0[k] * av_hi; a1 += rb1[k] * av_hi;
      b0 += rb0[k] * bv_hi; b1 += rb1[k] * bv_hi;
    }
    uint32* o = T0 + (((size_t)v * BINS + q) << 7) + c * 2;
    o[0] = packbf(ba + a0, a1 - a0);
    o[1] = packbf(bb + b0, b1 - b0);
  } else {
    int l = t - 1;
    const float* Wss = We_ss + l * 1024;
    const float* Wsv = We_sv + l * 1024;
    const float* WA = (c < 32) ? (We_vs + l * 512) : (We_vx + l * 512);
    const float* WB = (c < 32) ? (We_vv + l * 512) : nullptr;
    int cu = c & 31;
    float sa = 0, sb = 0, s0 = 0, s1 = 0, t0 = 0, t1 = 0;
    float ua = 0, ub = 0, u0 = 0, u1 = 0, w0 = 0, w1 = 0;
#pragma unroll
    for (int k = 0; k < 8; ++k) {
      float bt = bond_tab[v * 8 + k];
      float ss_lo = Wss[k * 64 + c], ss_hi = Wss[(8 + k) * 64 + c];
      float sv_lo = Wsv[k * 64 + c], sv_hi = Wsv[(8 + k) * 64 + c];
      sa += bt * ss_lo; sb += bt * sv_lo;
      s0 += rb0[k] * ss_hi; s1 += rb1[k] * ss_hi;
      t0 += rb0[k] * sv_hi; t1 += rb1[k] * sv_hi;
      float a_lo = WA[k * 32 + cu], a_hi = WA[(8 + k) * 32 + cu];
      ua += bt * a_lo;
      u0 += rb0[k] * a_hi; u1 += rb1[k] * a_hi;
      if (WB) {
        float b_lo = WB[k * 32 + cu], b_hi = WB[(8 + k) * 32 + cu];
        ub += bt * b_lo;
        w0 += rb0[k] * b_hi; w1 += rb1[k] * b_hi;
      }
    }
    uint32* o = TL + (size_t)l * TLU + (((size_t)v * BINS + q) << 8) + c * 4;
    o[0] = packbf(sa + s0, s1 - s0);
    o[1] = packbf(sb + t0, t1 - t0);
    o[2] = packbf(ua + u0, u1 - u0);
    o[3] = WB ? packbf(ub + w0, w1 - w0) : 0u;
  }
}

// ---------------- initial aggregation (3-stage pipeline, nt rec, bf16 a_v) ----------------
// a_v layout: [n][64] uint2 (bf16 x|y, z|0)
__global__ __launch_bounds__(256, 8) void k_agg0(
    const int* __restrict__ offsets, const float* __restrict__ rec8,
    const uint32* __restrict__ T0, const ushort16* __restrict__ s_bf,
    float* __restrict__ a_s, uint32* __restrict__ a_v) {
  int lane = threadIdx.x & 63;
  int n = blockIdx.x * 4 + (threadIdx.x >> 6);
  float acc = 0, a0 = 0, a1 = 0, a2 = 0;
  int beg = __builtin_amdgcn_readfirstlane(offsets[n]);
  int end = __builtin_amdgcn_readfirstlane(offsets[n + 1]);
  if (beg < end) {
    int last = end - 1;
    int e1 = (beg + 1 < end) ? beg + 1 : last;
    int e2 = (beg + 2 < end) ? beg + 2 : last;
    const float* p0 = rec8 + (size_t)beg * 8;
    const float* p1 = rec8 + (size_t)e1 * 8;
    const float* p2 = rec8 + (size_t)e2 * 8;
    float4 rA0 = ntl4(p0); float2 rB0 = ntl2(p0 + 4);
    float4 rA1 = ntl4(p1); float2 rB1 = ntl2(p1 + 4);
    float4 rA2 = ntl4(p2); float2 rB2 = ntl2(p2 + 4);
    uint2 t0 = *(const uint2*)(T0 + (__float_as_int(rB0.y) >> 1) + (lane << 1));
    ushort16 s0 = s_bf[((size_t)__float_as_int(rA0.x) << 6) + lane];
    uint2 t1 = *(const uint2*)(T0 + (__float_as_int(rB1.y) >> 1) + (lane << 1));
    ushort16 s1 = s_bf[((size_t)__float_as_int(rA1.x) << 6) + lane];
#pragma unroll 3
    for (int idx = beg; idx < end; ++idx) {
      uint2 t2 = *(const uint2*)(T0 + (__float_as_int(rB2.y) >> 1) + (lane << 1));
      ushort16 s2 = s_bf[((size_t)__float_as_int(rA2.x) << 6) + lane];
      int e3 = (idx + 3 < end) ? idx + 3 : last;
      const float* p3 = rec8 + (size_t)e3 * 8;
      float4 rA3 = ntl4(p3); float2 rB3 = ntl2(p3 + 4);
      float frac = rB0.x;
      float w0 = fmaf(frac, bflo(t0.x), bfhi(t0.x));
      float w1 = fmaf(frac, bflo(t0.y), bfhi(t0.y));
      float sv = __uint_as_float((uint32)s0 << 16);
      acc += w0 * sv;
      float t = w1 * sv;
      a0 += t * rA0.y; a1 += t * rA0.z; a2 += t * rA0.w;
      rA0 = rA1; rB0 = rB1; rA1 = rA2; rB1 = rB2; rA2 = rA3; rB2 = rB3;
      t0 = t1; s0 = s1; t1 = t2; s1 = s2;
    }
  }
  nts1(a_s + n * 64 + lane, acc * INV_NORM);
  ntsu2(a_v + ((size_t)n << 7) + (lane << 1),
        packbf(a0 * INV_NORM, a1 * INV_NORM), packbf(a2 * INV_NORM, 0.f));
}

// ---------------- layer aggregation (3-stage pipeline, nt rec, bf16 a_v) ----------------
// a_v layout: [n][128] uint2
__global__ __launch_bounds__(256, 8) void k_agg_layer(
    const float* __restrict__ cnoise, const float* __restrict__ nsw,
    const int* __restrict__ offsets, const float* __restrict__ rec8,
    const uint32* __restrict__ TL, const ushort16* __restrict__ sh_bf,
    const uint32* __restrict__ vh_bf,
    float* __restrict__ a_s, uint32* __restrict__ a_v) {
  int lane = threadIdx.x & 63;
  int n = blockIdx.x * 4 + (threadIdx.x >> 6);
  int vc = lane & 31;
  bool low = lane < 32;
  float cn = cnoise[0];
  float scale_s = 1.f + cn * nsw[lane];
  float scale_v = 1.f + cn * nsw[64 + vc];

  float ms = 0;
  float av0 = 0, av1 = 0, av2 = 0;
  float ms2 = 0;
  float b0 = 0, b1 = 0, b2 = 0;
  int beg = __builtin_amdgcn_readfirstlane(offsets[n]);
  int end = __builtin_amdgcn_readfirstlane(offsets[n + 1]);
  if (beg < end) {
    int last = end - 1;
    int e1 = (beg + 1 < end) ? beg + 1 : last;
    int e2 = (beg + 2 < end) ? beg + 2 : last;
    const float* p0 = rec8 + (size_t)beg * 8;
    const float* p1 = rec8 + (size_t)e1 * 8;
    const float* p2 = rec8 + (size_t)e2 * 8;
    float4 rA0 = ntl4(p0); float2 rB0 = ntl2(p0 + 4);
    float4 rA1 = ntl4(p1); float2 rB1 = ntl2(p1 + 4);
    float4 rA2 = ntl4(p2); float2 rB2 = ntl2(p2 + 4);
    uint4 t0 = *(const uint4*)(TL + __float_as_int(rB0.y) + (lane << 2));
    ushort16 s0 = sh_bf[((size_t)__float_as_int(rA0.x) << 6) + lane];
    uint2 v0 = *(const uint2*)(vh_bf + ((size_t)__float_as_int(rA0.x) << 6) + (vc << 1));
    uint4 t1 = *(const uint4*)(TL + __float_as_int(rB1.y) + (lane << 2));
    ushort16 s1 = sh_bf[((size_t)__float_as_int(rA1.x) << 6) + lane];
    uint2 v1 = *(const uint2*)(vh_bf + ((size_t)__float_as_int(rA1.x) << 6) + (vc << 1));
#pragma unroll 3
    for (int idx = beg; idx < end; ++idx) {
      uint4 t2 = *(const uint4*)(TL + __float_as_int(rB2.y) + (lane << 2));
      ushort16 s2 = sh_bf[((size_t)__float_as_int(rA2.x) << 6) + lane];
      uint2 v2 = *(const uint2*)(vh_bf + ((size_t)__float_as_int(rA2.x) << 6) + (vc << 1));
      int e3 = (idx + 3 < end) ? idx + 3 : last;
      const float* p3 = rec8 + (size_t)e3 * 8;
      float4 rA3 = ntl4(p3); float2 rB3 = ntl2(p3 + 4);
      float frac = rB0.x;
      float y0 = rA0.y, y1 = rA0.z, y2 = rA0.w;
      float wS  = fmaf(frac, bflo(t0.x), bfhi(t0.x));
      float wSV = fmaf(frac, bflo(t0.y), bfhi(t0.y));
      float wA  = fmaf(frac, bflo(t0.z), bfhi(t0.z));
      float wB  = fmaf(frac, bflo(t0.w), bfhi(t0.w));
      float ss = __uint_as_float((uint32)s0 << 16);
      float vx = bfhi(v0.x), vy = bflo(v0.x), vz = bfhi(v0.y);
      ms += wS * ss;
      float t = wSV * ss;
      av0 += t * y0; av1 += t * y1; av2 += t * y2;
      float vdot = vx * y0 + vy * y1 + vz * y2;
      ms2 += wA * vdot;  // garbage on high lanes, never written
      float cx = vy * y2 - vz * y1;
      float cy = vz * y0 - vx * y2;
      float cz = vx * y1 - vy * y0;
      float m0 = low ? vx : cx;
      float m1 = low ? vy : cy;
      float m2 = low ? vz : cz;
      float wM = low ? wB : wA;
      b0 += wM * m0; b1 += wM * m1; b2 += wM * m2;
      rA0 = rA1; rB0 = rB1; rA1 = rA2; rB1 = rB2; rA2 = rA3; rB2 = rB3;
      t0 = t1; s0 = s1; v0 = v1; t1 = t2; s1 = s2; v1 = v2;
    }
  }
  float fs = scale_s * INV_NORM;
  float fv = scale_v * INV_NORM;
  nts1(a_s + n * 96 + lane, ms * fs);
  uint32* avn = a_v + ((size_t)n << 8);
  ntsu2(avn + (lane << 1), packbf(av0 * fs, av1 * fs), packbf(av2 * fs, 0.f));
  if (low) {
    nts1(a_s + n * 96 + 64 + vc, ms2 * fv);
    ntsu2(avn + ((64 + vc) << 1), packbf(b0 * fv, b1 * fv), packbf(b2 * fv, 0.f));
  } else {
    ntsu2(avn + ((96 + vc) << 1), packbf(b0 * fv, b1 * fv), packbf(b2 * fv, 0.f));
  }
}

// ---------------- init_s: LDS-staged (bf16-packed weights, 20KB) ----------------
__global__ __launch_bounds__(256, 8) void k_init_s(
    const float* __restrict__ a_s, const float* __restrict__ s_feat,
    const float* __restrict__ Ws0, const float* __restrict__ Wself0,
    float* __restrict__ sh, ushort16* __restrict__ sh_bf) {
  __shared__ uint32 W1[32 * 64];  // 8KB: pair of rows (2k,2k+1)
  __shared__ uint32 W2[32 * 64];  // 8KB
  __shared__ float La[8 * 64];
  __shared__ float Lf[8 * 64];
  int tid = threadIdx.x;
  for (int i = tid; i < 32 * 64; i += 256) {
    int k = i >> 6, d = i & 63;
    W1[i] = packbf(Ws0[(2 * k) * 64 + d], Ws0[(2 * k + 1) * 64 + d]);
    W2[i] = packbf(Wself0[(2 * k) * 64 + d], Wself0[(2 * k + 1) * 64 + d]);
  }
  int base = blockIdx.x * 8;
  for (int i = tid; i < 512; i += 256) {
    La[i] = a_s[(size_t)base * 64 + i];
    Lf[i] = s_feat[(size_t)base * 64 + i];
  }
  __syncthreads();
  int d = tid & 63, g = tid >> 6;
  int n0 = base + g * 2;
  const float* A0 = La + g * 128;
  const float* A1 = A0 + 64;
  const float* F0 = Lf + g * 128;
  const float* F1 = F0 + 64;
  float a0 = 0, a1 = 0;
#pragma unroll 8
  for (int k = 0; k < 32; ++k) {
    uint32 w1 = W1[k * 64 + d], w2 = W2[k * 64 + d];
    int c = 2 * k;
    a0 += A0[c] * bfhi(w1) + A0[c + 1] * bflo(w1) + F0[c] * bfhi(w2) + F0[c + 1] * bflo(w2);
    a1 += A1[c] * bfhi(w1) + A1[c + 1] * bflo(w1) + F1[c] * bfhi(w2) + F1[c + 1] * bflo(w2);
  }
  sh[(size_t)n0 * 64 + d] = a0;
  sh[(size_t)(n0 + 1) * 64 + d] = a1;
  sh_bf[(size_t)n0 * 64 + d] = f2bf(a0);
  sh_bf[(size_t)(n0 + 1) * 64 + d] = f2bf(a1);
}

// ---------------- init_v: LDS-staged (bf16-packed weights, 4KB) ----------------
__global__ __launch_bounds__(256, 8) void k_init_v(
    const uint32* __restrict__ a_v, const float* __restrict__ Wv0,
    float* __restrict__ vh, uint32* __restrict__ vh_bf) {
  __shared__ uint32 W[32 * 32];  // 4KB: pair of rows
  int tid = threadIdx.x;
  for (int i = tid; i < 32 * 32; i += 256) {
    int k = i >> 5, d = i & 31;
    W[i] = packbf(Wv0[(2 * k) * 32 + d], Wv0[(2 * k + 1) * 32 + d]);
  }
  __syncthreads();
  int d = tid & 31, g = tid >> 5;
  int n = blockIdx.x * 8 + g;
  const uint2* av = (const uint2*)a_v + ((size_t)n << 6);
  float x = 0, y = 0, z = 0;
#pragma unroll 8
  for (int k = 0; k < 32; ++k) {
    uint32 w = W[k * 32 + d];
    uint2 e0 = av[2 * k], e1 = av[2 * k + 1];
    float w0 = bfhi(w), w1 = bflo(w);
    x += bfhi(e0.x) * w0 + bfhi(e1.x) * w1;
    y += bflo(e0.x) * w0 + bflo(e1.x) * w1;
    z += bfhi(e0.y) * w0 + bfhi(e1.y) * w1;
  }
  *(float4*)(vh + ((size_t)n << 7) + (d << 2)) = make_float4(x, y, z, 0.f);
  *(uint2*)(vh_bf + ((size_t)n << 6) + (d << 1)) = make_uint2(packbf(x, y), packbf(z, 0.f));
}

// ---------------- mix_s: LDS-staged (bf16-packed weights, 23KB) ----------------
__global__ __launch_bounds__(256, 6) void k_mix_s(
    const float* __restrict__ a_s, const float* __restrict__ sh_in,
    const float* __restrict__ Wmix_s, const float* __restrict__ Wself_s,
    const float* __restrict__ nsw, const float* __restrict__ skw,
    const float* __restrict__ skb, const float* __restrict__ cnoise,
    float* __restrict__ sh_out, ushort16* __restrict__ sh_bf_out) {
  __shared__ uint32 Wm[48 * 64];   // 12KB: rows (2k,2k+1) packed
  __shared__ uint32 Wsf[32 * 64];  // 8KB (scale folded in)
  __shared__ float La[8 * 96];     // 3KB
  int tid = threadIdx.x;
  float cn = cnoise[0];
  for (int i = tid; i < 48 * 64; i += 256) {
    int k = i >> 6, d = i & 63;
    Wm[i] = packbf(Wmix_s[(2 * k) * 64 + d], Wmix_s[(2 * k + 1) * 64 + d]);
  }
  for (int i = tid; i < 32 * 64; i += 256) {
    int k = i >> 6, d = i & 63;
    float sc0 = 1.f + cn * nsw[2 * k];
    float sc1 = 1.f + cn * nsw[2 * k + 1];
    Wsf[i] = packbf(Wself_s[(2 * k) * 64 + d] * sc0, Wself_s[(2 * k + 1) * 64 + d] * sc1);
  }
  int base = blockIdx.x * 8;
  for (int i = tid; i < 8 * 96; i += 256) La[i] = a_s[(size_t)base * 96 + i];
  __syncthreads();
  int d = tid & 63, g = tid >> 6;
  int n0 = base + g * 2;
  const float* A0 = La + (g * 2) * 96;
  const float* A1 = A0 + 96;
  const float* s0p = sh_in + (size_t)n0 * 64;
  const float* s1p = s0p + 64;
  float acc0 = 0, acc1 = 0;
#pragma unroll 8
  for (int k = 0; k < 48; ++k) {
    uint32 w = Wm[k * 64 + d];
    int c = 2 * k;
    float wh = bfhi(w), wl = bflo(w);
    acc0 += A0[c] * wh + A0[c + 1] * wl;
    acc1 += A1[c] * wh + A1[c + 1] * wl;
  }
#pragma unroll 8
  for (int k = 0; k < 32; ++k) {
    uint32 w = Wsf[k * 64 + d];
    int c = 2 * k;
    float wh = bfhi(w), wl = bflo(w);
    acc0 += s0p[c] * wh + s0p[c + 1] * wl;
    acc1 += s1p[c] * wh + s1p[c + 1] * wl;
  }
  float g1 = sigmoidf_(skb[d] + cn * skw[d]);
  float g2 = sigmoidf_(skb[64 + d] + cn * skw[64 + d]);
  float o0 = g1 * s0p[d] + g2 * acc0;
  float o1 = g1 * s1p[d] + g2 * acc1;
  sh_out[(size_t)n0 * 64 + d] = o0;
  sh_out[(size_t)(n0 + 1) * 64 + d] = o1;
  sh_bf_out[(size_t)n0 * 64 + d] = f2bf(o0);
  sh_bf_out[(size_t)(n0 + 1) * 64 + d] = f2bf(o1);
}

// ---------------- mix_v: LDS-staged (bf16-packed weights, 10KB) ----------------
__global__ __launch_bounds__(256, 8) void k_mix_v(
    const uint32* __restrict__ a_v, const float* __restrict__ vh_in,
    const float* __restrict__ Wmix_v, const float* __restrict__ Wself_v,
    const float* __restrict__ nsw, const float* __restrict__ skw,
    const float* __restrict__ skb, const float* __restrict__ cnoise,
    float* __restrict__ vh_out, uint32* __restrict__ vh_bf_out) {
  __shared__ uint32 Wm[64 * 32];   // 8KB
  __shared__ uint32 Wsf[16 * 32];  // 2KB (scale folded in)
  int tid = threadIdx.x;
  float cn = cnoise[0];
  for (int i = tid; i < 64 * 32; i += 256) {
    int k = i >> 5, d = i & 31;
    Wm[i] = packbf(Wmix_v[(2 * k) * 32 + d], Wmix_v[(2 * k + 1) * 32 + d]);
  }
  for (int i = tid; i < 16 * 32; i += 256) {
    int k = i >> 5, d = i & 31;
    float sc0 = 1.f + cn * nsw[64 + 2 * k];
    float sc1 = 1.f + cn * nsw[64 + 2 * k + 1];
    Wsf[i] = packbf(Wself_v[(2 * k) * 32 + d] * sc0, Wself_v[(2 * k + 1) * 32 + d] * sc1);
  }
  __syncthreads();
  int d = tid & 31, g = tid >> 5;
  int n = blockIdx.x * 8 + g;
  const uint2* av = (const uint2*)a_v + ((size_t)n << 7);
  const float4* vr = (const float4*)(vh_in + ((size_t)n << 7));
  float x = 0, y = 0, z = 0;
#pragma unroll 8
  for (int k = 0; k < 64; ++k) {
    uint32 w = Wm[k * 32 + d];
    uint2 e0 = av[2 * k], e1 = av[2 * k + 1];
    float w0 = bfhi(w), w1 = bflo(w);
    x += bfhi(e0.x) * w0 + bfhi(e1.x) * w1;
    y += bflo(e0.x) * w0 + bflo(e1.x) * w1;
    z += bfhi(e0.y) * w0 + bfhi(e1.y) * w1;
  }
#pragma unroll 8
  for (int k = 0; k < 16; ++k) {
    uint32 w = Wsf[k * 32 + d];
    float4 e0 = vr[2 * k], e1 = vr[2 * k + 1];
    float w0 = bfhi(w), w1 = bflo(w);
    x += e0.x * w0 + e1.x * w1;
    y += e0.y * w0 + e1.y * w1;
    z += e0.z * w0 + e1.z * w1;
  }
  float g3 = sigmoidf_(skb[128 + d] + cn * skw[128 + d]);
  float g4 = sigmoidf_(skb[160 + d] + cn * skw[160 + d]);
  float4 vi = vr[d];
  float ox = g3 * vi.x + g4 * x;
  float oy = g3 * vi.y + g4 * y;
  float oz = g3 * vi.z + g4 * z;
  *(float4*)(vh_out + ((size_t)n << 7) + (d << 2)) = make_float4(ox, oy, oz, 0.f);
  *(uint2*)(vh_bf_out + ((size_t)n << 6) + (d << 1)) = make_uint2(packbf(ox, oy), packbf(oz, 0.f));
}

// ---------------- output ----------------
__global__ void k_out(const float* __restrict__ vh, const float* __restrict__ w_out,
                      const float* __restrict__ gain, float* __restrict__ out) {
  int tid = blockIdx.x * 256 + threadIdx.x;  // < NA*3
  int n = tid / 3, i = tid - n * 3;
  float acc = 0;
  for (int c = 0; c < 32; ++c) acc += vh[((size_t)n << 7) + c * 4 + i] * w_out[c];
  out[tid] = acc * gain[0];
}

extern "C" void kernel_launch(void* const* d_in, const int* in_sizes, int n_in,
                              void* d_out, int out_size, void* d_ws, size_t ws_size,
                              hipStream_t stream) {
  (void)in_sizes; (void)n_in; (void)out_size; (void)ws_size;
  const float* pos     = (const float*)d_in[0];
  const float* cn      = (const float*)d_in[1];
  const int*   types   = (const int*)d_in[2];
  const int*   rad     = (const int*)d_in[3];
  const int*   bon     = (const int*)d_in[4];
  const float* atom_tab= (const float*)d_in[5];
  const float* bond_tab= (const float*)d_in[6];
  const float* ns0_w   = (const float*)d_in[7];
  const float* We0     = (const float*)d_in[8];
  const float* We1     = (const float*)d_in[9];
  const float* Wself0  = (const float*)d_in[10];
  const float* Ws0     = (const float*)d_in[11];
  const float* Wv0     = (const float*)d_in[12];
  const float* ns_w    = (const float*)d_in[13];
  const float* We_ss   = (const float*)d_in[14];
  const float* We_vs   = (const float*)d_in[15];
  const float* We_sv   = (const float*)d_in[16];
  const float* We_vv   = (const float*)d_in[17];
  const float* We_vx   = (const float*)d_in[18];
  const float* Wmix_s  = (const float*)d_in[19];
  const float* Wmix_v  = (const float*)d_in[20];
  const float* Wself_s = (const float*)d_in[21];
  const float* Wself_v = (const float*)d_in[22];
  const float* skip_w  = (const float*)d_in[23];
  const float* skip_b  = (const float*)d_in[24];
  const float* w_out   = (const float*)d_in[25];
  const float* gain    = (const float*)d_in[26];

  char* ws = (char*)d_ws;
  size_t o = 0;
  auto alloc = [&](size_t bytes) -> void* {
    void* p = ws + o;
    o += (bytes + 255) & ~(size_t)255;
    return p;
  };
  float* s_feat  = (float*)alloc((size_t)NA * 64 * 4);
  ushort16* s_bf = (ushort16*)alloc((size_t)NA * 64 * 2);
  float* a_s     = (float*)alloc((size_t)NA * 96 * 4);
  uint32* a_v    = (uint32*)alloc((size_t)NA * 256 * 4);  // [n][128] uint2; agg0 uses [n][64] uint2
  float* sh0     = (float*)alloc((size_t)NA * 64 * 4);
  float* sh1     = (float*)alloc((size_t)NA * 64 * 4);
  ushort16* shbf0= (ushort16*)alloc((size_t)NA * 64 * 2);
  ushort16* shbf1= (ushort16*)alloc((size_t)NA * 64 * 2);
  float* vh0     = (float*)alloc((size_t)NA * 128 * 4);  // [n][32][4]
  float* vh1     = (float*)alloc((size_t)NA * 128 * 4);
  uint32* vhbf0  = (uint32*)alloc((size_t)NA * 64 * 4);  // [n][32][2] uints
  uint32* vhbf1  = (uint32*)alloc((size_t)NA * 64 * 4);
  int* count     = (int*)alloc((size_t)NA * 4);
  int* partial   = (int*)alloc((size_t)64 * 4);
  int* offsets   = (int*)alloc((size_t)(NA + 1) * 4);
  int* cursor    = (int*)alloc((size_t)NA * 4);
  float* rec8    = (float*)alloc((size_t)ET * 32);
  uint32* T0     = (uint32*)alloc((size_t)T0U * 4);
  uint32* TL     = (uint32*)alloc((size_t)2 * TLU * 4);
  float* shb[2]  = {sh0, sh1};
  ushort16* shbf[2] = {shbf0, shbf1};
  float* vhb[2]  = {vh0, vh1};
  uint32* vhbf[2]= {vhbf0, vhbf1};

  // CSR build + tables
  hipMemsetAsync(count, 0, (size_t)NA * 4, stream);
  k_hist<<<ET / 256, 256, 0, stream>>>(rad, bon, count);
  k_scan1<<<64, 256, 0, stream>>>(count, partial);
  k_scan2<<<1, 1, 0, stream>>>(partial);
  k_scan3<<<64, 256, 0, stream>>>(count, partial, offsets, cursor);
  k_fill_embed<<<ET / 256 + NA * 64 / 256, 256, 0, stream>>>(
      rad, bon, cursor, pos, rec8, atom_tab, types, ns0_w, cn, s_feat, s_bf);
  k_build<<<dim3(BINS, 3, 2), 64, 0, stream>>>(We0, We1, We_ss, We_vs, We_sv, We_vv, We_vx,
                                               bond_tab, T0, TL);

  k_agg0<<<NA / 4, 256, 0, stream>>>(offsets, rec8, T0, s_bf, a_s, a_v);
  k_init_s<<<NA / 8, 256, 0, stream>>>(a_s, s_feat, Ws0, Wself0, shb[0], shbf[0]);
  k_init_v<<<NA / 8, 256, 0, stream>>>(a_v, Wv0, vhb[0], vhbf[0]);

  for (int l = 0; l < 2; ++l) {
    int bin = l & 1, bout = 1 - bin;
    k_agg_layer<<<NA / 4, 256, 0, stream>>>(
        cn, ns_w + l * 96, offsets, rec8, TL + (size_t)l * TLU, shbf[bin], vhbf[bin], a_s, a_v);
    k_mix_s<<<NA / 8, 256, 0, stream>>>(
        a_s, shb[bin], Wmix_s + l * 96 * 64, Wself_s + l * 64 * 64,
        ns_w + l * 96, skip_w + l * 192, skip_b + l * 192, cn, shb[bout], shbf[bout]);
    k_mix_v<<<NA / 8, 256, 0, stream>>>(
        a_v, vhb[bin], Wmix_v + l * 128 * 32, Wself_v + l * 32 * 32,
        ns_w + l * 96, skip_w + l * 192, skip_b + l * 192, cn, vhb[bout], vhbf[bout]);
  }
  k_out<<<NA * 3 / 256, 256, 0, stream>>>(vhb[0], w_out, gain, (float*)d_out);
}

// Round 17
// 499.522 us; speedup vs baseline: 1.0185x; 1.0073x over previous
//
#include <hip/hip_runtime.h>
#include <math.h>

#define NA 16384
#define ER 524288
#define EB 32768
#define ET 557056
#define INV_NORM 0.17149858514250882f   // 1/sqrt((ER+EB)/NA) = 1/sqrt(34)
#define SQRT3 1.7320508075688772f
#define RB_STEP (1.5f/9.0f)
#define BINS 512
#define DMAX 2.5f
#define INV_H ((float)BINS / DMAX)
#define T0U (2 * BINS * 128)    // agg0 table: [2][BINS][64][2] uints
#define TLU (2 * BINS * 256)    // layer table: [2][BINS][64][4] uints

typedef unsigned int uint32;
typedef unsigned short ushort16;
typedef float vf4 __attribute__((ext_vector_type(4)));
typedef float vf2 __attribute__((ext_vector_type(2)));
typedef unsigned int vu2 __attribute__((ext_vector_type(2)));

__device__ __forceinline__ float sigmoidf_(float x) { return 1.f / (1.f + __expf(-x)); }

__device__ __forceinline__ ushort16 f2bf(float x) {
  uint32 u = __float_as_uint(x);
  u = u + 0x7FFFu + ((u >> 16) & 1u);
  return (ushort16)(u >> 16);
}
__device__ __forceinline__ uint32 packbf(float hi, float lo) {
  return ((uint32)f2bf(hi) << 16) | (uint32)f2bf(lo);
}
__device__ __forceinline__ float bfhi(uint32 u) { return __uint_as_float(u & 0xFFFF0000u); }
__device__ __forceinline__ float bflo(uint32 u) { return __uint_as_float(u << 16); }

// nontemporal helpers (streaming data must not evict the gather working set)
__device__ __forceinline__ float4 ntl4(const float* p) {
  vf4 v = __builtin_nontemporal_load((const vf4*)p);
  return make_float4(v.x, v.y, v.z, v.w);
}
__device__ __forceinline__ float2 ntl2(const float* p) {
  vf2 v = __builtin_nontemporal_load((const vf2*)p);
  return make_float2(v.x, v.y);
}
__device__ __forceinline__ void nts4(float* p, float a, float b, float c, float d) {
  vf4 v; v.x = a; v.y = b; v.z = c; v.w = d;
  __builtin_nontemporal_store(v, (vf4*)p);
}
__device__ __forceinline__ void nts2(float* p, float a, float b) {
  vf2 v; v.x = a; v.y = b;
  __builtin_nontemporal_store(v, (vf2*)p);
}
__device__ __forceinline__ void ntsu2(uint32* p, uint32 a, uint32 b) {
  vu2 v; v.x = a; v.y = b;
  __builtin_nontemporal_store(v, (vu2*)p);
}
__device__ __forceinline__ void nts1(float* p, float a) {
  __builtin_nontemporal_store(a, p);
}

// ---------------- CSR build ----------------
__global__ void k_hist(const int* __restrict__ rad, const int* __restrict__ bon, int* __restrict__ count) {
  int e = blockIdx.x * 256 + threadIdx.x;
  int d = (e < ER) ? rad[ER + e] : bon[EB + (e - ER)];
  atomicAdd(&count[d], 1);
}

__global__ void k_scan1(const int* __restrict__ count, int* __restrict__ partial) {
  __shared__ int red[256];
  int b = blockIdx.x, t = threadIdx.x;
  red[t] = count[b * 256 + t];
  __syncthreads();
  for (int s = 128; s > 0; s >>= 1) {
    if (t < s) red[t] += red[t + s];
    __syncthreads();
  }
  if (t == 0) partial[b] = red[0];
}

__global__ void k_scan2(int* __restrict__ partial) {
  int run = 0;
  for (int i = 0; i < 64; ++i) { int c = partial[i]; partial[i] = run; run += c; }
}

__global__ void k_scan3(const int* __restrict__ count, const int* __restrict__ partial,
                        int* __restrict__ offsets, int* __restrict__ cursor) {
  __shared__ int sc[256];
  int b = blockIdx.x, t = threadIdx.x;
  int v = count[b * 256 + t];
  sc[t] = v;
  __syncthreads();
  for (int off = 1; off < 256; off <<= 1) {
    int x = (t >= off) ? sc[t - off] : 0;
    __syncthreads();
    sc[t] += x;
    __syncthreads();
  }
  int excl = sc[t] - v + partial[b];
  offsets[b * 256 + t] = excl;
  cursor[b * 256 + t] = excl;
  if (b == 63 && t == 255) offsets[NA] = excl + v;
}

// ---------------- fused: slot-scatter (4B) | embedding ----------------
__global__ void k_fill_embed(const int* __restrict__ rad, const int* __restrict__ bon,
                             int* __restrict__ cursor, int* __restrict__ sorted,
                             const float* __restrict__ atom_tab, const int* __restrict__ types,
                             const float* __restrict__ ns0_w, const float* __restrict__ cnoise,
                             float* __restrict__ s_feat, ushort16* __restrict__ s_bf) {
  if (blockIdx.x < ET / 256) {
    int e = blockIdx.x * 256 + threadIdx.x;
    int d = (e < ER) ? rad[ER + e] : bon[EB + (e - ER)];
    int slot = atomicAdd(&cursor[d], 1);
    sorted[slot] = e;
  } else {
    int tid = (blockIdx.x - ET / 256) * 256 + threadIdx.x;
    int n = tid >> 6, c = tid & 63;
    float cn = cnoise[0];
    float v = atom_tab[types[n] * 64 + c] * (1.f + cn * ns0_w[c]);
    s_feat[tid] = v;
    s_bf[tid] = f2bf(v);
  }
}

// ---------------- reorder: coalesced sorted read -> coalesced rec write ----------------
// record[idx] (32B): {src, Y0, Y1, Y2, frac, qoffL, pad, pad}; agg0 offset = qoffL>>1
__global__ void k_reorder(const int* __restrict__ sorted,
                          const int* __restrict__ rad, const int* __restrict__ bon,
                          const float* __restrict__ pos, float* __restrict__ rec8) {
  int idx = blockIdx.x * 256 + threadIdx.x;
  int e = sorted[idx];
  int src, dst, v;
  if (e < ER) { src = rad[e]; dst = rad[ER + e]; v = 0; }
  else        { src = bon[e - ER]; dst = bon[EB + e - ER]; v = 1; }
  float dx = pos[src * 3] - pos[dst * 3];
  float dy = pos[src * 3 + 1] - pos[dst * 3 + 1];
  float dz = pos[src * 3 + 2] - pos[dst * 3 + 2];
  float dist = sqrtf(dx * dx + dy * dy + dz * dz + 1e-12f);
  float inv = 1.f / dist;
  float fq = fminf(dist * INV_H, BINS - 1.001f);
  int q = (int)fq;
  float frac = fq - (float)q;
  int qoffL = (v * BINS + q) << 8;
  float* rp = rec8 + (size_t)idx * 8;
  nts4(rp, __int_as_float(src), SQRT3 * dx * inv, SQRT3 * dy * inv, SQRT3 * dz * inv);
  nts2(rp + 4, frac, __int_as_float(qoffL));
}

// ---------------- bf16 tables, bond base folded ----------------
__global__ void k_build(const float* __restrict__ We0, const float* __restrict__ We1,
                        const float* __restrict__ We_ss, const float* __restrict__ We_vs,
                        const float* __restrict__ We_sv, const float* __restrict__ We_vv,
                        const float* __restrict__ We_vx, const float* __restrict__ bond_tab,
                        uint32* __restrict__ T0, uint32* __restrict__ TL) {
  int q = blockIdx.x, t = blockIdx.y, v = blockIdx.z, c = threadIdx.x;
  float d0 = q * (DMAX / BINS), d1 = (q + 1) * (DMAX / BINS);
  float rb0[8], rb1[8];
#pragma unroll
  for (int k = 0; k < 8; ++k) {
    float f0 = (d0 - (k + 1) * RB_STEP) * (1.f / RB_STEP);
    float f1 = (d1 - (k + 1) * RB_STEP) * (1.f / RB_STEP);
    rb0[k] = 1.12f * __expf(-f0 * f0);
    rb1[k] = 1.12f * __expf(-f1 * f1);
  }
  if (t == 0) {
    float ba = 0, bb = 0, a0 = 0, a1 = 0, b0 = 0, b1 = 0;
#pragma unroll
    for (int k = 0; k < 8; ++k) {
      float bt = bond_tab[v * 8 + k];
      float av_lo = We0[k * 64 + c], av_hi = We0[(8 + k) * 64 + c];
      float bv_lo = We1[k * 64 + c], bv_hi = We1[(8 + k) * 64 + c];
      ba += bt * av_lo; bb += bt * bv_lo;
      a0 += rb0[k] * av_hi; a1 += rb1[k] * av_hi;
      b0 += rb0[k] * bv_hi; b1 += rb1[k] * bv_hi;
    }
    uint32* o = T0 + (((size_t)v * BINS + q) << 7) + c * 2;
    o[0] = packbf(ba + a0, a1 - a0);
    o[1] = packbf(bb + b0, b1 - b0);
  } else {
    int l = t - 1;
    const float* Wss = We_ss + l * 1024;
    const float* Wsv = We_sv + l * 1024;
    const float* WA = (c < 32) ? (We_vs + l * 512) : (We_vx + l * 512);
    const float* WB = (c < 32) ? (We_vv + l * 512) : nullptr;
    int cu = c & 31;
    float sa = 0, sb = 0, s0 = 0, s1 = 0, t0 = 0, t1 = 0;
    float ua = 0, ub = 0, u0 = 0, u1 = 0, w0 = 0, w1 = 0;
#pragma unroll
    for (int k = 0; k < 8; ++k) {
      float bt = bond_tab[v * 8 + k];
      float ss_lo = Wss[k * 64 + c], ss_hi = Wss[(8 + k) * 64 + c];
      float sv_lo = Wsv[k * 64 + c], sv_hi = Wsv[(8 + k) * 64 + c];
      sa += bt * ss_lo; sb += bt * sv_lo;
      s0 += rb0[k] * ss_hi; s1 += rb1[k] * ss_hi;
      t0 += rb0[k] * sv_hi; t1 += rb1[k] * sv_hi;
      float a_lo = WA[k * 32 + cu], a_hi = WA[(8 + k) * 32 + cu];
      ua += bt * a_lo;
      u0 += rb0[k] * a_hi; u1 += rb1[k] * a_hi;
      if (WB) {
        float b_lo = WB[k * 32 + cu], b_hi = WB[(8 + k) * 32 + cu];
        ub += bt * b_lo;
        w0 += rb0[k] * b_hi; w1 += rb1[k] * b_hi;
      }
    }
    uint32* o = TL + (size_t)l * TLU + (((size_t)v * BINS + q) << 8) + c * 4;
    o[0] = packbf(sa + s0, s1 - s0);
    o[1] = packbf(sb + t0, t1 - t0);
    o[2] = packbf(ua + u0, u1 - u0);
    o[3] = WB ? packbf(ub + w0, w1 - w0) : 0u;
  }
}

// ---------------- initial aggregation (3-stage pipeline, nt rec, bf16 a_v) ----------------
// a_v layout: [n][64] uint2 (bf16 x|y, z|0)
__global__ __launch_bounds__(256, 8) void k_agg0(
    const int* __restrict__ offsets, const float* __restrict__ rec8,
    const uint32* __restrict__ T0, const ushort16* __restrict__ s_bf,
    float* __restrict__ a_s, uint32* __restrict__ a_v) {
  int lane = threadIdx.x & 63;
  int n = blockIdx.x * 4 + (threadIdx.x >> 6);
  float acc = 0, a0 = 0, a1 = 0, a2 = 0;
  int beg = __builtin_amdgcn_readfirstlane(offsets[n]);
  int end = __builtin_amdgcn_readfirstlane(offsets[n + 1]);
  if (beg < end) {
    int last = end - 1;
    int e1 = (beg + 1 < end) ? beg + 1 : last;
    int e2 = (beg + 2 < end) ? beg + 2 : last;
    const float* p0 = rec8 + (size_t)beg * 8;
    const float* p1 = rec8 + (size_t)e1 * 8;
    const float* p2 = rec8 + (size_t)e2 * 8;
    float4 rA0 = ntl4(p0); float2 rB0 = ntl2(p0 + 4);
    float4 rA1 = ntl4(p1); float2 rB1 = ntl2(p1 + 4);
    float4 rA2 = ntl4(p2); float2 rB2 = ntl2(p2 + 4);
    uint2 t0 = *(const uint2*)(T0 + (__float_as_int(rB0.y) >> 1) + (lane << 1));
    ushort16 s0 = s_bf[((size_t)__float_as_int(rA0.x) << 6) + lane];
    uint2 t1 = *(const uint2*)(T0 + (__float_as_int(rB1.y) >> 1) + (lane << 1));
    ushort16 s1 = s_bf[((size_t)__float_as_int(rA1.x) << 6) + lane];
#pragma unroll 3
    for (int idx = beg; idx < end; ++idx) {
      uint2 t2 = *(const uint2*)(T0 + (__float_as_int(rB2.y) >> 1) + (lane << 1));
      ushort16 s2 = s_bf[((size_t)__float_as_int(rA2.x) << 6) + lane];
      int e3 = (idx + 3 < end) ? idx + 3 : last;
      const float* p3 = rec8 + (size_t)e3 * 8;
      float4 rA3 = ntl4(p3); float2 rB3 = ntl2(p3 + 4);
      float frac = rB0.x;
      float w0 = fmaf(frac, bflo(t0.x), bfhi(t0.x));
      float w1 = fmaf(frac, bflo(t0.y), bfhi(t0.y));
      float sv = __uint_as_float((uint32)s0 << 16);
      acc += w0 * sv;
      float t = w1 * sv;
      a0 += t * rA0.y; a1 += t * rA0.z; a2 += t * rA0.w;
      rA0 = rA1; rB0 = rB1; rA1 = rA2; rB1 = rB2; rA2 = rA3; rB2 = rB3;
      t0 = t1; s0 = s1; t1 = t2; s1 = s2;
    }
  }
  nts1(a_s + n * 64 + lane, acc * INV_NORM);
  ntsu2(a_v + ((size_t)n << 7) + (lane << 1),
        packbf(a0 * INV_NORM, a1 * INV_NORM), packbf(a2 * INV_NORM, 0.f));
}

// ---------------- layer aggregation (3-stage pipeline, nt rec, bf16 a_v) ----------------
// a_v layout: [n][128] uint2
__global__ __launch_bounds__(256, 8) void k_agg_layer(
    const float* __restrict__ cnoise, const float* __restrict__ nsw,
    const int* __restrict__ offsets, const float* __restrict__ rec8,
    const uint32* __restrict__ TL, const ushort16* __restrict__ sh_bf,
    const uint32* __restrict__ vh_bf,
    float* __restrict__ a_s, uint32* __restrict__ a_v) {
  int lane = threadIdx.x & 63;
  int n = blockIdx.x * 4 + (threadIdx.x >> 6);
  int vc = lane & 31;
  bool low = lane < 32;
  float cn = cnoise[0];
  float scale_s = 1.f + cn * nsw[lane];
  float scale_v = 1.f + cn * nsw[64 + vc];

  float ms = 0;
  float av0 = 0, av1 = 0, av2 = 0;
  float ms2 = 0;
  float b0 = 0, b1 = 0, b2 = 0;
  int beg = __builtin_amdgcn_readfirstlane(offsets[n]);
  int end = __builtin_amdgcn_readfirstlane(offsets[n + 1]);
  if (beg < end) {
    int last = end - 1;
    int e1 = (beg + 1 < end) ? beg + 1 : last;
    int e2 = (beg + 2 < end) ? beg + 2 : last;
    const float* p0 = rec8 + (size_t)beg * 8;
    const float* p1 = rec8 + (size_t)e1 * 8;
    const float* p2 = rec8 + (size_t)e2 * 8;
    float4 rA0 = ntl4(p0); float2 rB0 = ntl2(p0 + 4);
    float4 rA1 = ntl4(p1); float2 rB1 = ntl2(p1 + 4);
    float4 rA2 = ntl4(p2); float2 rB2 = ntl2(p2 + 4);
    uint4 t0 = *(const uint4*)(TL + __float_as_int(rB0.y) + (lane << 2));
    ushort16 s0 = sh_bf[((size_t)__float_as_int(rA0.x) << 6) + lane];
    uint2 v0 = *(const uint2*)(vh_bf + ((size_t)__float_as_int(rA0.x) << 6) + (vc << 1));
    uint4 t1 = *(const uint4*)(TL + __float_as_int(rB1.y) + (lane << 2));
    ushort16 s1 = sh_bf[((size_t)__float_as_int(rA1.x) << 6) + lane];
    uint2 v1 = *(const uint2*)(vh_bf + ((size_t)__float_as_int(rA1.x) << 6) + (vc << 1));
#pragma unroll 3
    for (int idx = beg; idx < end; ++idx) {
      uint4 t2 = *(const uint4*)(TL + __float_as_int(rB2.y) + (lane << 2));
      ushort16 s2 = sh_bf[((size_t)__float_as_int(rA2.x) << 6) + lane];
      uint2 v2 = *(const uint2*)(vh_bf + ((size_t)__float_as_int(rA2.x) << 6) + (vc << 1));
      int e3 = (idx + 3 < end) ? idx + 3 : last;
      const float* p3 = rec8 + (size_t)e3 * 8;
      float4 rA3 = ntl4(p3); float2 rB3 = ntl2(p3 + 4);
      float frac = rB0.x;
      float y0 = rA0.y, y1 = rA0.z, y2 = rA0.w;
      float wS  = fmaf(frac, bflo(t0.x), bfhi(t0.x));
      float wSV = fmaf(frac, bflo(t0.y), bfhi(t0.y));
      float wA  = fmaf(frac, bflo(t0.z), bfhi(t0.z));
      float wB  = fmaf(frac, bflo(t0.w), bfhi(t0.w));
      float ss = __uint_as_float((uint32)s0 << 16);
      float vx = bfhi(v0.x), vy = bflo(v0.x), vz = bfhi(v0.y);
      ms += wS * ss;
      float t = wSV * ss;
      av0 += t * y0; av1 += t * y1; av2 += t * y2;
      float vdot = vx * y0 + vy * y1 + vz * y2;
      ms2 += wA * vdot;  // garbage on high lanes, never written
      float cx = vy * y2 - vz * y1;
      float cy = vz * y0 - vx * y2;
      float cz = vx * y1 - vy * y0;
      float m0 = low ? vx : cx;
      float m1 = low ? vy : cy;
      float m2 = low ? vz : cz;
      float wM = low ? wB : wA;
      b0 += wM * m0; b1 += wM * m1; b2 += wM * m2;
      rA0 = rA1; rB0 = rB1; rA1 = rA2; rB1 = rB2; rA2 = rA3; rB2 = rB3;
      t0 = t1; s0 = s1; v0 = v1; t1 = t2; s1 = s2; v1 = v2;
    }
  }
  float fs = scale_s * INV_NORM;
  float fv = scale_v * INV_NORM;
  nts1(a_s + n * 96 + lane, ms * fs);
  uint32* avn = a_v + ((size_t)n << 8);
  ntsu2(avn + (lane << 1), packbf(av0 * fs, av1 * fs), packbf(av2 * fs, 0.f));
  if (low) {
    nts1(a_s + n * 96 + 64 + vc, ms2 * fv);
    ntsu2(avn + ((64 + vc) << 1), packbf(b0 * fv, b1 * fv), packbf(b2 * fv, 0.f));
  } else {
    ntsu2(avn + ((96 + vc) << 1), packbf(b0 * fv, b1 * fv), packbf(b2 * fv, 0.f));
  }
}

// ---------------- init_s: LDS-staged (bf16-packed weights, 20KB) ----------------
__global__ __launch_bounds__(256, 8) void k_init_s(
    const float* __restrict__ a_s, const float* __restrict__ s_feat,
    const float* __restrict__ Ws0, const float* __restrict__ Wself0,
    float* __restrict__ sh, ushort16* __restrict__ sh_bf) {
  __shared__ uint32 W1[32 * 64];  // 8KB: pair of rows (2k,2k+1)
  __shared__ uint32 W2[32 * 64];  // 8KB
  __shared__ float La[8 * 64];
  __shared__ float Lf[8 * 64];
  int tid = threadIdx.x;
  for (int i = tid; i < 32 * 64; i += 256) {
    int k = i >> 6, d = i & 63;
    W1[i] = packbf(Ws0[(2 * k) * 64 + d], Ws0[(2 * k + 1) * 64 + d]);
    W2[i] = packbf(Wself0[(2 * k) * 64 + d], Wself0[(2 * k + 1) * 64 + d]);
  }
  int base = blockIdx.x * 8;
  for (int i = tid; i < 512; i += 256) {
    La[i] = a_s[(size_t)base * 64 + i];
    Lf[i] = s_feat[(size_t)base * 64 + i];
  }
  __syncthreads();
  int d = tid & 63, g = tid >> 6;
  int n0 = base + g * 2;
  const float* A0 = La + g * 128;
  const float* A1 = A0 + 64;
  const float* F0 = Lf + g * 128;
  const float* F1 = F0 + 64;
  float a0 = 0, a1 = 0;
#pragma unroll 8
  for (int k = 0; k < 32; ++k) {
    uint32 w1 = W1[k * 64 + d], w2 = W2[k * 64 + d];
    int c = 2 * k;
    a0 += A0[c] * bfhi(w1) + A0[c + 1] * bflo(w1) + F0[c] * bfhi(w2) + F0[c + 1] * bflo(w2);
    a1 += A1[c] * bfhi(w1) + A1[c + 1] * bflo(w1) + F1[c] * bfhi(w2) + F1[c + 1] * bflo(w2);
  }
  sh[(size_t)n0 * 64 + d] = a0;
  sh[(size_t)(n0 + 1) * 64 + d] = a1;
  sh_bf[(size_t)n0 * 64 + d] = f2bf(a0);
  sh_bf[(size_t)(n0 + 1) * 64 + d] = f2bf(a1);
}

// ---------------- init_v: LDS-staged (bf16-packed weights, 4KB) ----------------
__global__ __launch_bounds__(256, 8) void k_init_v(
    const uint32* __restrict__ a_v, const float* __restrict__ Wv0,
    float* __restrict__ vh, uint32* __restrict__ vh_bf) {
  __shared__ uint32 W[32 * 32];  // 4KB: pair of rows
  int tid = threadIdx.x;
  for (int i = tid; i < 32 * 32; i += 256) {
    int k = i >> 5, d = i & 31;
    W[i] = packbf(Wv0[(2 * k) * 32 + d], Wv0[(2 * k + 1) * 32 + d]);
  }
  __syncthreads();
  int d = tid & 31, g = tid >> 5;
  int n = blockIdx.x * 8 + g;
  const uint2* av = (const uint2*)a_v + ((size_t)n << 6);
  float x = 0, y = 0, z = 0;
#pragma unroll 8
  for (int k = 0; k < 32; ++k) {
    uint32 w = W[k * 32 + d];
    uint2 e0 = av[2 * k], e1 = av[2 * k + 1];
    float w0 = bfhi(w), w1 = bflo(w);
    x += bfhi(e0.x) * w0 + bfhi(e1.x) * w1;
    y += bflo(e0.x) * w0 + bflo(e1.x) * w1;
    z += bfhi(e0.y) * w0 + bfhi(e1.y) * w1;
  }
  *(float4*)(vh + ((size_t)n << 7) + (d << 2)) = make_float4(x, y, z, 0.f);
  *(uint2*)(vh_bf + ((size_t)n << 6) + (d << 1)) = make_uint2(packbf(x, y), packbf(z, 0.f));
}

// ---------------- mix_s: LDS-staged (bf16-packed weights, 23KB) ----------------
__global__ __launch_bounds__(256, 6) void k_mix_s(
    const float* __restrict__ a_s, const float* __restrict__ sh_in,
    const float* __restrict__ Wmix_s, const float* __restrict__ Wself_s,
    const float* __restrict__ nsw, const float* __restrict__ skw,
    const float* __restrict__ skb, const float* __restrict__ cnoise,
    float* __restrict__ sh_out, ushort16* __restrict__ sh_bf_out) {
  __shared__ uint32 Wm[48 * 64];   // 12KB: rows (2k,2k+1) packed
  __shared__ uint32 Wsf[32 * 64];  // 8KB (scale folded in)
  __shared__ float La[8 * 96];     // 3KB
  int tid = threadIdx.x;
  float cn = cnoise[0];
  for (int i = tid; i < 48 * 64; i += 256) {
    int k = i >> 6, d = i & 63;
    Wm[i] = packbf(Wmix_s[(2 * k) * 64 + d], Wmix_s[(2 * k + 1) * 64 + d]);
  }
  for (int i = tid; i < 32 * 64; i += 256) {
    int k = i >> 6, d = i & 63;
    float sc0 = 1.f + cn * nsw[2 * k];
    float sc1 = 1.f + cn * nsw[2 * k + 1];
    Wsf[i] = packbf(Wself_s[(2 * k) * 64 + d] * sc0, Wself_s[(2 * k + 1) * 64 + d] * sc1);
  }
  int base = blockIdx.x * 8;
  for (int i = tid; i < 8 * 96; i += 256) La[i] = a_s[(size_t)base * 96 + i];
  __syncthreads();
  int d = tid & 63, g = tid >> 6;
  int n0 = base + g * 2;
  const float* A0 = La + (g * 2) * 96;
  const float* A1 = A0 + 96;
  const float* s0p = sh_in + (size_t)n0 * 64;
  const float* s1p = s0p + 64;
  float acc0 = 0, acc1 = 0;
#pragma unroll 8
  for (int k = 0; k < 48; ++k) {
    uint32 w = Wm[k * 64 + d];
    int c = 2 * k;
    float wh = bfhi(w), wl = bflo(w);
    acc0 += A0[c] * wh + A0[c + 1] * wl;
    acc1 += A1[c] * wh + A1[c + 1] * wl;
  }
#pragma unroll 8
  for (int k = 0; k < 32; ++k) {
    uint32 w = Wsf[k * 64 + d];
    int c = 2 * k;
    float wh = bfhi(w), wl = bflo(w);
    acc0 += s0p[c] * wh + s0p[c + 1] * wl;
    acc1 += s1p[c] * wh + s1p[c + 1] * wl;
  }
  float g1 = sigmoidf_(skb[d] + cn * skw[d]);
  float g2 = sigmoidf_(skb[64 + d] + cn * skw[64 + d]);
  float o0 = g1 * s0p[d] + g2 * acc0;
  float o1 = g1 * s1p[d] + g2 * acc1;
  sh_out[(size_t)n0 * 64 + d] = o0;
  sh_out[(size_t)(n0 + 1) * 64 + d] = o1;
  sh_bf_out[(size_t)n0 * 64 + d] = f2bf(o0);
  sh_bf_out[(size_t)(n0 + 1) * 64 + d] = f2bf(o1);
}

// ---------------- mix_v: LDS-staged (+ optional fused output) ----------------
__global__ __launch_bounds__(256, 8) void k_mix_v(
    const uint32* __restrict__ a_v, const float* __restrict__ vh_in,
    const float* __restrict__ Wmix_v, const float* __restrict__ Wself_v,
    const float* __restrict__ nsw, const float* __restrict__ skw,
    const float* __restrict__ skb, const float* __restrict__ cnoise,
    float* __restrict__ vh_out, uint32* __restrict__ vh_bf_out,
    const float* __restrict__ w_out, const float* __restrict__ gain,
    float* __restrict__ out, int doOut) {
  __shared__ uint32 Wm[64 * 32];   // 8KB
  __shared__ uint32 Wsf[16 * 32];  // 2KB (scale folded in)
  int tid = threadIdx.x;
  float cn = cnoise[0];
  for (int i = tid; i < 64 * 32; i += 256) {
    int k = i >> 5, d = i & 31;
    Wm[i] = packbf(Wmix_v[(2 * k) * 32 + d], Wmix_v[(2 * k + 1) * 32 + d]);
  }
  for (int i = tid; i < 16 * 32; i += 256) {
    int k = i >> 5, d = i & 31;
    float sc0 = 1.f + cn * nsw[64 + 2 * k];
    float sc1 = 1.f + cn * nsw[64 + 2 * k + 1];
    Wsf[i] = packbf(Wself_v[(2 * k) * 32 + d] * sc0, Wself_v[(2 * k + 1) * 32 + d] * sc1);
  }
  __syncthreads();
  int d = tid & 31, g = tid >> 5;
  int n = blockIdx.x * 8 + g;
  const uint2* av = (const uint2*)a_v + ((size_t)n << 7);
  const float4* vr = (const float4*)(vh_in + ((size_t)n << 7));
  float x = 0, y = 0, z = 0;
#pragma unroll 8
  for (int k = 0; k < 64; ++k) {
    uint32 w = Wm[k * 32 + d];
    uint2 e0 = av[2 * k], e1 = av[2 * k + 1];
    float w0 = bfhi(w), w1 = bflo(w);
    x += bfhi(e0.x) * w0 + bfhi(e1.x) * w1;
    y += bflo(e0.x) * w0 + bflo(e1.x) * w1;
    z += bfhi(e0.y) * w0 + bfhi(e1.y) * w1;
  }
#pragma unroll 8
  for (int k = 0; k < 16; ++k) {
    uint32 w = Wsf[k * 32 + d];
    float4 e0 = vr[2 * k], e1 = vr[2 * k + 1];
    float w0 = bfhi(w), w1 = bflo(w);
    x += e0.x * w0 + e1.x * w1;
    y += e0.y * w0 + e1.y * w1;
    z += e0.z * w0 + e1.z * w1;
  }
  float g3 = sigmoidf_(skb[128 + d] + cn * skw[128 + d]);
  float g4 = sigmoidf_(skb[160 + d] + cn * skw[160 + d]);
  float4 vi = vr[d];
  float ox = g3 * vi.x + g4 * x;
  float oy = g3 * vi.y + g4 * y;
  float oz = g3 * vi.z + g4 * z;
  *(float4*)(vh_out + ((size_t)n << 7) + (d << 2)) = make_float4(ox, oy, oz, 0.f);
  *(uint2*)(vh_bf_out + ((size_t)n << 6) + (d << 1)) = make_uint2(packbf(ox, oy), packbf(oz, 0.f));
  if (doOut) {
    float wv = w_out[d];
    float rx = wv * ox, ry = wv * oy, rz = wv * oz;
#pragma unroll
    for (int m = 16; m > 0; m >>= 1) {
      rx += __shfl_xor(rx, m, 32);
      ry += __shfl_xor(ry, m, 32);
      rz += __shfl_xor(rz, m, 32);
    }
    if (d == 0) {
      float gn = gain[0];
      float* op = out + (size_t)n * 3;
      op[0] = rx * gn; op[1] = ry * gn; op[2] = rz * gn;
    }
  }
}

extern "C" void kernel_launch(void* const* d_in, const int* in_sizes, int n_in,
                              void* d_out, int out_size, void* d_ws, size_t ws_size,
                              hipStream_t stream) {
  (void)in_sizes; (void)n_in; (void)out_size; (void)ws_size;
  const float* pos     = (const float*)d_in[0];
  const float* cn      = (const float*)d_in[1];
  const int*   types   = (const int*)d_in[2];
  const int*   rad     = (const int*)d_in[3];
  const int*   bon     = (const int*)d_in[4];
  const float* atom_tab= (const float*)d_in[5];
  const float* bond_tab= (const float*)d_in[6];
  const float* ns0_w   = (const float*)d_in[7];
  const float* We0     = (const float*)d_in[8];
  const float* We1     = (const float*)d_in[9];
  const float* Wself0  = (const float*)d_in[10];
  const float* Ws0     = (const float*)d_in[11];
  const float* Wv0     = (const float*)d_in[12];
  const float* ns_w    = (const float*)d_in[13];
  const float* We_ss   = (const float*)d_in[14];
  const float* We_vs   = (const float*)d_in[15];
  const float* We_sv   = (const float*)d_in[16];
  const float* We_vv   = (const float*)d_in[17];
  const float* We_vx   = (const float*)d_in[18];
  const float* Wmix_s  = (const float*)d_in[19];
  const float* Wmix_v  = (const float*)d_in[20];
  const float* Wself_s = (const float*)d_in[21];
  const float* Wself_v = (const float*)d_in[22];
  const float* skip_w  = (const float*)d_in[23];
  const float* skip_b  = (const float*)d_in[24];
  const float* w_out   = (const float*)d_in[25];
  const float* gain    = (const float*)d_in[26];

  char* ws = (char*)d_ws;
  size_t o = 0;
  auto alloc = [&](size_t bytes) -> void* {
    void* p = ws + o;
    o += (bytes + 255) & ~(size_t)255;
    return p;
  };
  float* s_feat  = (float*)alloc((size_t)NA * 64 * 4);
  ushort16* s_bf = (ushort16*)alloc((size_t)NA * 64 * 2);
  float* a_s     = (float*)alloc((size_t)NA * 96 * 4);
  uint32* a_v    = (uint32*)alloc((size_t)NA * 256 * 4);  // [n][128] uint2; agg0 uses [n][64] uint2
  float* sh0     = (float*)alloc((size_t)NA * 64 * 4);
  float* sh1     = (float*)alloc((size_t)NA * 64 * 4);
  ushort16* shbf0= (ushort16*)alloc((size_t)NA * 64 * 2);
  ushort16* shbf1= (ushort16*)alloc((size_t)NA * 64 * 2);
  float* vh0     = (float*)alloc((size_t)NA * 128 * 4);  // [n][32][4]
  float* vh1     = (float*)alloc((size_t)NA * 128 * 4);
  uint32* vhbf0  = (uint32*)alloc((size_t)NA * 64 * 4);  // [n][32][2] uints
  uint32* vhbf1  = (uint32*)alloc((size_t)NA * 64 * 4);
  int* count     = (int*)alloc((size_t)NA * 4);
  int* partial   = (int*)alloc((size_t)64 * 4);
  int* offsets   = (int*)alloc((size_t)(NA + 1) * 4);
  int* cursor    = (int*)alloc((size_t)NA * 4);
  int* sorted    = (int*)alloc((size_t)ET * 4);
  float* rec8    = (float*)alloc((size_t)ET * 32);
  uint32* T0     = (uint32*)alloc((size_t)T0U * 4);
  uint32* TL     = (uint32*)alloc((size_t)2 * TLU * 4);
  float* shb[2]  = {sh0, sh1};
  ushort16* shbf[2] = {shbf0, shbf1};
  float* vhb[2]  = {vh0, vh1};
  uint32* vhbf[2]= {vhbf0, vhbf1};

  // CSR build + tables
  hipMemsetAsync(count, 0, (size_t)NA * 4, stream);
  k_hist<<<ET / 256, 256, 0, stream>>>(rad, bon, count);
  k_scan1<<<64, 256, 0, stream>>>(count, partial);
  k_scan2<<<1, 1, 0, stream>>>(partial);
  k_scan3<<<64, 256, 0, stream>>>(count, partial, offsets, cursor);
  k_fill_embed<<<ET / 256 + NA * 64 / 256, 256, 0, stream>>>(
      rad, bon, cursor, sorted, atom_tab, types, ns0_w, cn, s_feat, s_bf);
  k_reorder<<<ET / 256, 256, 0, stream>>>(sorted, rad, bon, pos, rec8);
  k_build<<<dim3(BINS, 3, 2), 64, 0, stream>>>(We0, We1, We_ss, We_vs, We_sv, We_vv, We_vx,
                                               bond_tab, T0, TL);

  k_agg0<<<NA / 4, 256, 0, stream>>>(offsets, rec8, T0, s_bf, a_s, a_v);
  k_init_s<<<NA / 8, 256, 0, stream>>>(a_s, s_feat, Ws0, Wself0, shb[0], shbf[0]);
  k_init_v<<<NA / 8, 256, 0, stream>>>(a_v, Wv0, vhb[0], vhbf[0]);

  for (int l = 0; l < 2; ++l) {
    int bin = l & 1, bout = 1 - bin;
    k_agg_layer<<<NA / 4, 256, 0, stream>>>(
        cn, ns_w + l * 96, offsets, rec8, TL + (size_t)l * TLU, shbf[bin], vhbf[bin], a_s, a_v);
    k_mix_s<<<NA / 8, 256, 0, stream>>>(
        a_s, shb[bin], Wmix_s + l * 96 * 64, Wself_s + l * 64 * 64,
        ns_w + l * 96, skip_w + l * 192, skip_b + l * 192, cn, shb[bout], shbf[bout]);
    k_mix_v<<<NA / 8, 256, 0, stream>>>(
        a_v, vhb[bin], Wmix_v + l * 128 * 32, Wself_v + l * 32 * 32,
        ns_w + l * 96, skip_w + l * 192, skip_b + l * 192, cn, vhb[bout], vhbf[bout],
        w_out, gain, (float*)d_out, l == 1);
  }
}

// Round 18
// 483.161 us; speedup vs baseline: 1.0530x; 1.0339x over previous
//
#include <hip/hip_runtime.h>
#include <math.h>

#define NA 16384
#define ER 524288
#define EB 32768
#define ET 557056
#define INV_NORM 0.17149858514250882f   // 1/sqrt((ER+EB)/NA) = 1/sqrt(34)
#define SQRT3 1.7320508075688772f
#define RB_STEP (1.5f/9.0f)
#define BINS 512
#define DMAX 2.5f
#define INV_H ((float)BINS / DMAX)
#define T0U (2 * BINS * 128)    // agg0 table: [2][BINS][64][2] uints
#define TLU (2 * BINS * 256)    // layer table: [2][BINS][64][4] uints

typedef unsigned int uint32;
typedef unsigned short ushort16;
typedef float vf4 __attribute__((ext_vector_type(4)));
typedef float vf2 __attribute__((ext_vector_type(2)));

__device__ __forceinline__ float sigmoidf_(float x) { return 1.f / (1.f + __expf(-x)); }

__device__ __forceinline__ ushort16 f2bf(float x) {
  uint32 u = __float_as_uint(x);
  u = u + 0x7FFFu + ((u >> 16) & 1u);
  return (ushort16)(u >> 16);
}
__device__ __forceinline__ uint32 packbf(float hi, float lo) {
  return ((uint32)f2bf(hi) << 16) | (uint32)f2bf(lo);
}
__device__ __forceinline__ float bfhi(uint32 u) { return __uint_as_float(u & 0xFFFF0000u); }
__device__ __forceinline__ float bflo(uint32 u) { return __uint_as_float(u << 16); }

// nontemporal helpers — ONLY for the rec stream (written once, streamed; must not
// evict the gather working set). Producer->consumer intermediates (a_s/a_v) use
// plain cached stores so the following mix/init kernels hit L2.
__device__ __forceinline__ float4 ntl4(const float* p) {
  vf4 v = __builtin_nontemporal_load((const vf4*)p);
  return make_float4(v.x, v.y, v.z, v.w);
}
__device__ __forceinline__ float2 ntl2(const float* p) {
  vf2 v = __builtin_nontemporal_load((const vf2*)p);
  return make_float2(v.x, v.y);
}
__device__ __forceinline__ void nts4(float* p, float a, float b, float c, float d) {
  vf4 v; v.x = a; v.y = b; v.z = c; v.w = d;
  __builtin_nontemporal_store(v, (vf4*)p);
}
__device__ __forceinline__ void nts2(float* p, float a, float b) {
  vf2 v; v.x = a; v.y = b;
  __builtin_nontemporal_store(v, (vf2*)p);
}

// ---------------- CSR build ----------------
__global__ void k_hist(const int* __restrict__ rad, const int* __restrict__ bon, int* __restrict__ count) {
  int e = blockIdx.x * 256 + threadIdx.x;
  int d = (e < ER) ? rad[ER + e] : bon[EB + (e - ER)];
  atomicAdd(&count[d], 1);
}

__global__ void k_scan1(const int* __restrict__ count, int* __restrict__ partial) {
  __shared__ int red[256];
  int b = blockIdx.x, t = threadIdx.x;
  red[t] = count[b * 256 + t];
  __syncthreads();
  for (int s = 128; s > 0; s >>= 1) {
    if (t < s) red[t] += red[t + s];
    __syncthreads();
  }
  if (t == 0) partial[b] = red[0];
}

__global__ void k_scan2(int* __restrict__ partial) {
  int run = 0;
  for (int i = 0; i < 64; ++i) { int c = partial[i]; partial[i] = run; run += c; }
}

__global__ void k_scan3(const int* __restrict__ count, const int* __restrict__ partial,
                        int* __restrict__ offsets, int* __restrict__ cursor) {
  __shared__ int sc[256];
  int b = blockIdx.x, t = threadIdx.x;
  int v = count[b * 256 + t];
  sc[t] = v;
  __syncthreads();
  for (int off = 1; off < 256; off <<= 1) {
    int x = (t >= off) ? sc[t - off] : 0;
    __syncthreads();
    sc[t] += x;
    __syncthreads();
  }
  int excl = sc[t] - v + partial[b];
  offsets[b * 256 + t] = excl;
  cursor[b * 256 + t] = excl;
  if (b == 63 && t == 255) offsets[NA] = excl + v;
}

// ---------------- fused: slot-scatter (4B) | embedding ----------------
__global__ void k_fill_embed(const int* __restrict__ rad, const int* __restrict__ bon,
                             int* __restrict__ cursor, int* __restrict__ sorted,
                             const float* __restrict__ atom_tab, const int* __restrict__ types,
                             const float* __restrict__ ns0_w, const float* __restrict__ cnoise,
                             float* __restrict__ s_feat, ushort16* __restrict__ s_bf) {
  if (blockIdx.x < ET / 256) {
    int e = blockIdx.x * 256 + threadIdx.x;
    int d = (e < ER) ? rad[ER + e] : bon[EB + (e - ER)];
    int slot = atomicAdd(&cursor[d], 1);
    sorted[slot] = e;
  } else {
    int tid = (blockIdx.x - ET / 256) * 256 + threadIdx.x;
    int n = tid >> 6, c = tid & 63;
    float cn = cnoise[0];
    float v = atom_tab[types[n] * 64 + c] * (1.f + cn * ns0_w[c]);
    s_feat[tid] = v;
    s_bf[tid] = f2bf(v);
  }
}

// ---------------- reorder: coalesced sorted read -> coalesced rec write ----------------
// record[idx] (32B): {src, Y0, Y1, Y2, frac, qoffL, pad, pad}; agg0 offset = qoffL>>1
__global__ void k_reorder(const int* __restrict__ sorted,
                          const int* __restrict__ rad, const int* __restrict__ bon,
                          const float* __restrict__ pos, float* __restrict__ rec8) {
  int idx = blockIdx.x * 256 + threadIdx.x;
  int e = sorted[idx];
  int src, dst, v;
  if (e < ER) { src = rad[e]; dst = rad[ER + e]; v = 0; }
  else        { src = bon[e - ER]; dst = bon[EB + e - ER]; v = 1; }
  float dx = pos[src * 3] - pos[dst * 3];
  float dy = pos[src * 3 + 1] - pos[dst * 3 + 1];
  float dz = pos[src * 3 + 2] - pos[dst * 3 + 2];
  float dist = sqrtf(dx * dx + dy * dy + dz * dz + 1e-12f);
  float inv = 1.f / dist;
  float fq = fminf(dist * INV_H, BINS - 1.001f);
  int q = (int)fq;
  float frac = fq - (float)q;
  int qoffL = (v * BINS + q) << 8;
  float* rp = rec8 + (size_t)idx * 8;
  nts4(rp, __int_as_float(src), SQRT3 * dx * inv, SQRT3 * dy * inv, SQRT3 * dz * inv);
  nts2(rp + 4, frac, __int_as_float(qoffL));
}

// ---------------- bf16 tables, bond base folded ----------------
__global__ void k_build(const float* __restrict__ We0, const float* __restrict__ We1,
                        const float* __restrict__ We_ss, const float* __restrict__ We_vs,
                        const float* __restrict__ We_sv, const float* __restrict__ We_vv,
                        const float* __restrict__ We_vx, const float* __restrict__ bond_tab,
                        uint32* __restrict__ T0, uint32* __restrict__ TL) {
  int q = blockIdx.x, t = blockIdx.y, v = blockIdx.z, c = threadIdx.x;
  float d0 = q * (DMAX / BINS), d1 = (q + 1) * (DMAX / BINS);
  float rb0[8], rb1[8];
#pragma unroll
  for (int k = 0; k < 8; ++k) {
    float f0 = (d0 - (k + 1) * RB_STEP) * (1.f / RB_STEP);
    float f1 = (d1 - (k + 1) * RB_STEP) * (1.f / RB_STEP);
    rb0[k] = 1.12f * __expf(-f0 * f0);
    rb1[k] = 1.12f * __expf(-f1 * f1);
  }
  if (t == 0) {
    float ba = 0, bb = 0, a0 = 0, a1 = 0, b0 = 0, b1 = 0;
#pragma unroll
    for (int k = 0; k < 8; ++k) {
      float bt = bond_tab[v * 8 + k];
      float av_lo = We0[k * 64 + c], av_hi = We0[(8 + k) * 64 + c];
      float bv_lo = We1[k * 64 + c], bv_hi = We1[(8 + k) * 64 + c];
      ba += bt * av_lo; bb += bt * bv_lo;
      a0 += rb0[k] * av_hi; a1 += rb1[k] * av_hi;
      b0 += rb0[k] * bv_hi; b1 += rb1[k] * bv_hi;
    }
    uint32* o = T0 + (((size_t)v * BINS + q) << 7) + c * 2;
    o[0] = packbf(ba + a0, a1 - a0);
    o[1] = packbf(bb + b0, b1 - b0);
  } else {
    int l = t - 1;
    const float* Wss = We_ss + l * 1024;
    const float* Wsv = We_sv + l * 1024;
    const float* WA = (c < 32) ? (We_vs + l * 512) : (We_vx + l * 512);
    const float* WB = (c < 32) ? (We_vv + l * 512) : nullptr;
    int cu = c & 31;
    float sa = 0, sb = 0, s0 = 0, s1 = 0, t0 = 0, t1 = 0;
    float ua = 0, ub = 0, u0 = 0, u1 = 0, w0 = 0, w1 = 0;
#pragma unroll
    for (int k = 0; k < 8; ++k) {
      float bt = bond_tab[v * 8 + k];
      float ss_lo = Wss[k * 64 + c], ss_hi = Wss[(8 + k) * 64 + c];
      float sv_lo = Wsv[k * 64 + c], sv_hi = Wsv[(8 + k) * 64 + c];
      sa += bt * ss_lo; sb += bt * sv_lo;
      s0 += rb0[k] * ss_hi; s1 += rb1[k] * ss_hi;
      t0 += rb0[k] * sv_hi; t1 += rb1[k] * sv_hi;
      float a_lo = WA[k * 32 + cu], a_hi = WA[(8 + k) * 32 + cu];
      ua += bt * a_lo;
      u0 += rb0[k] * a_hi; u1 += rb1[k] * a_hi;
      if (WB) {
        float b_lo = WB[k * 32 + cu], b_hi = WB[(8 + k) * 32 + cu];
        ub += bt * b_lo;
        w0 += rb0[k] * b_hi; w1 += rb1[k] * b_hi;
      }
    }
    uint32* o = TL + (size_t)l * TLU + (((size_t)v * BINS + q) << 8) + c * 4;
    o[0] = packbf(sa + s0, s1 - s0);
    o[1] = packbf(sb + t0, t1 - t0);
    o[2] = packbf(ua + u0, u1 - u0);
    o[3] = WB ? packbf(ub + w0, w1 - w0) : 0u;
  }
}

// ---------------- initial aggregation (3-stage pipeline, nt rec, cached outputs) ----------------
// a_v layout: [n][64] uint2 (bf16 x|y, z|0)
__global__ __launch_bounds__(256, 8) void k_agg0(
    const int* __restrict__ offsets, const float* __restrict__ rec8,
    const uint32* __restrict__ T0, const ushort16* __restrict__ s_bf,
    float* __restrict__ a_s, uint32* __restrict__ a_v) {
  int lane = threadIdx.x & 63;
  int n = blockIdx.x * 4 + (threadIdx.x >> 6);
  float acc = 0, a0 = 0, a1 = 0, a2 = 0;
  int beg = __builtin_amdgcn_readfirstlane(offsets[n]);
  int end = __builtin_amdgcn_readfirstlane(offsets[n + 1]);
  if (beg < end) {
    int last = end - 1;
    int e1 = (beg + 1 < end) ? beg + 1 : last;
    int e2 = (beg + 2 < end) ? beg + 2 : last;
    const float* p0 = rec8 + (size_t)beg * 8;
    const float* p1 = rec8 + (size_t)e1 * 8;
    const float* p2 = rec8 + (size_t)e2 * 8;
    float4 rA0 = ntl4(p0); float2 rB0 = ntl2(p0 + 4);
    float4 rA1 = ntl4(p1); float2 rB1 = ntl2(p1 + 4);
    float4 rA2 = ntl4(p2); float2 rB2 = ntl2(p2 + 4);
    uint2 t0 = *(const uint2*)(T0 + (__float_as_int(rB0.y) >> 1) + (lane << 1));
    ushort16 s0 = s_bf[((size_t)__float_as_int(rA0.x) << 6) + lane];
    uint2 t1 = *(const uint2*)(T0 + (__float_as_int(rB1.y) >> 1) + (lane << 1));
    ushort16 s1 = s_bf[((size_t)__float_as_int(rA1.x) << 6) + lane];
#pragma unroll 3
    for (int idx = beg; idx < end; ++idx) {
      uint2 t2 = *(const uint2*)(T0 + (__float_as_int(rB2.y) >> 1) + (lane << 1));
      ushort16 s2 = s_bf[((size_t)__float_as_int(rA2.x) << 6) + lane];
      int e3 = (idx + 3 < end) ? idx + 3 : last;
      const float* p3 = rec8 + (size_t)e3 * 8;
      float4 rA3 = ntl4(p3); float2 rB3 = ntl2(p3 + 4);
      float frac = rB0.x;
      float w0 = fmaf(frac, bflo(t0.x), bfhi(t0.x));
      float w1 = fmaf(frac, bflo(t0.y), bfhi(t0.y));
      float sv = __uint_as_float((uint32)s0 << 16);
      acc += w0 * sv;
      float t = w1 * sv;
      a0 += t * rA0.y; a1 += t * rA0.z; a2 += t * rA0.w;
      rA0 = rA1; rB0 = rB1; rA1 = rA2; rB1 = rB2; rA2 = rA3; rB2 = rB3;
      t0 = t1; s0 = s1; t1 = t2; s1 = s2;
    }
  }
  a_s[n * 64 + lane] = acc * INV_NORM;
  *(uint2*)(a_v + ((size_t)n << 7) + (lane << 1)) =
      make_uint2(packbf(a0 * INV_NORM, a1 * INV_NORM), packbf(a2 * INV_NORM, 0.f));
}

// ---------------- layer aggregation (3-stage pipeline, nt rec, cached outputs) ----------------
// a_v layout: [n][128] uint2
__global__ __launch_bounds__(256, 8) void k_agg_layer(
    const float* __restrict__ cnoise, const float* __restrict__ nsw,
    const int* __restrict__ offsets, const float* __restrict__ rec8,
    const uint32* __restrict__ TL, const ushort16* __restrict__ sh_bf,
    const uint32* __restrict__ vh_bf,
    float* __restrict__ a_s, uint32* __restrict__ a_v) {
  int lane = threadIdx.x & 63;
  int n = blockIdx.x * 4 + (threadIdx.x >> 6);
  int vc = lane & 31;
  bool low = lane < 32;
  float cn = cnoise[0];
  float scale_s = 1.f + cn * nsw[lane];
  float scale_v = 1.f + cn * nsw[64 + vc];

  float ms = 0;
  float av0 = 0, av1 = 0, av2 = 0;
  float ms2 = 0;
  float b0 = 0, b1 = 0, b2 = 0;
  int beg = __builtin_amdgcn_readfirstlane(offsets[n]);
  int end = __builtin_amdgcn_readfirstlane(offsets[n + 1]);
  if (beg < end) {
    int last = end - 1;
    int e1 = (beg + 1 < end) ? beg + 1 : last;
    int e2 = (beg + 2 < end) ? beg + 2 : last;
    const float* p0 = rec8 + (size_t)beg * 8;
    const float* p1 = rec8 + (size_t)e1 * 8;
    const float* p2 = rec8 + (size_t)e2 * 8;
    float4 rA0 = ntl4(p0); float2 rB0 = ntl2(p0 + 4);
    float4 rA1 = ntl4(p1); float2 rB1 = ntl2(p1 + 4);
    float4 rA2 = ntl4(p2); float2 rB2 = ntl2(p2 + 4);
    uint4 t0 = *(const uint4*)(TL + __float_as_int(rB0.y) + (lane << 2));
    ushort16 s0 = sh_bf[((size_t)__float_as_int(rA0.x) << 6) + lane];
    uint2 v0 = *(const uint2*)(vh_bf + ((size_t)__float_as_int(rA0.x) << 6) + (vc << 1));
    uint4 t1 = *(const uint4*)(TL + __float_as_int(rB1.y) + (lane << 2));
    ushort16 s1 = sh_bf[((size_t)__float_as_int(rA1.x) << 6) + lane];
    uint2 v1 = *(const uint2*)(vh_bf + ((size_t)__float_as_int(rA1.x) << 6) + (vc << 1));
#pragma unroll 3
    for (int idx = beg; idx < end; ++idx) {
      uint4 t2 = *(const uint4*)(TL + __float_as_int(rB2.y) + (lane << 2));
      ushort16 s2 = sh_bf[((size_t)__float_as_int(rA2.x) << 6) + lane];
      uint2 v2 = *(const uint2*)(vh_bf + ((size_t)__float_as_int(rA2.x) << 6) + (vc << 1));
      int e3 = (idx + 3 < end) ? idx + 3 : last;
      const float* p3 = rec8 + (size_t)e3 * 8;
      float4 rA3 = ntl4(p3); float2 rB3 = ntl2(p3 + 4);
      float frac = rB0.x;
      float y0 = rA0.y, y1 = rA0.z, y2 = rA0.w;
      float wS  = fmaf(frac, bflo(t0.x), bfhi(t0.x));
      float wSV = fmaf(frac, bflo(t0.y), bfhi(t0.y));
      float wA  = fmaf(frac, bflo(t0.z), bfhi(t0.z));
      float wB  = fmaf(frac, bflo(t0.w), bfhi(t0.w));
      float ss = __uint_as_float((uint32)s0 << 16);
      float vx = bfhi(v0.x), vy = bflo(v0.x), vz = bfhi(v0.y);
      ms += wS * ss;
      float t = wSV * ss;
      av0 += t * y0; av1 += t * y1; av2 += t * y2;
      float vdot = vx * y0 + vy * y1 + vz * y2;
      ms2 += wA * vdot;  // garbage on high lanes, never written
      float cx = vy * y2 - vz * y1;
      float cy = vz * y0 - vx * y2;
      float cz = vx * y1 - vy * y0;
      float m0 = low ? vx : cx;
      float m1 = low ? vy : cy;
      float m2 = low ? vz : cz;
      float wM = low ? wB : wA;
      b0 += wM * m0; b1 += wM * m1; b2 += wM * m2;
      rA0 = rA1; rB0 = rB1; rA1 = rA2; rB1 = rB2; rA2 = rA3; rB2 = rB3;
      t0 = t1; s0 = s1; v0 = v1; t1 = t2; s1 = s2; v1 = v2;
    }
  }
  float fs = scale_s * INV_NORM;
  float fv = scale_v * INV_NORM;
  a_s[n * 96 + lane] = ms * fs;
  uint32* avn = a_v + ((size_t)n << 8);
  *(uint2*)(avn + (lane << 1)) = make_uint2(packbf(av0 * fs, av1 * fs), packbf(av2 * fs, 0.f));
  if (low) {
    a_s[n * 96 + 64 + vc] = ms2 * fv;
    *(uint2*)(avn + ((64 + vc) << 1)) = make_uint2(packbf(b0 * fv, b1 * fv), packbf(b2 * fv, 0.f));
  } else {
    *(uint2*)(avn + ((96 + vc) << 1)) = make_uint2(packbf(b0 * fv, b1 * fv), packbf(b2 * fv, 0.f));
  }
}

// ---------------- init_s: LDS-staged (bf16-packed weights, 20KB) ----------------
__global__ __launch_bounds__(256, 8) void k_init_s(
    const float* __restrict__ a_s, const float* __restrict__ s_feat,
    const float* __restrict__ Ws0, const float* __restrict__ Wself0,
    float* __restrict__ sh, ushort16* __restrict__ sh_bf) {
  __shared__ uint32 W1[32 * 64];  // 8KB: pair of rows (2k,2k+1)
  __shared__ uint32 W2[32 * 64];  // 8KB
  __shared__ float La[8 * 64];
  __shared__ float Lf[8 * 64];
  int tid = threadIdx.x;
  for (int i = tid; i < 32 * 64; i += 256) {
    int k = i >> 6, d = i & 63;
    W1[i] = packbf(Ws0[(2 * k) * 64 + d], Ws0[(2 * k + 1) * 64 + d]);
    W2[i] = packbf(Wself0[(2 * k) * 64 + d], Wself0[(2 * k + 1) * 64 + d]);
  }
  int base = blockIdx.x * 8;
  for (int i = tid; i < 512; i += 256) {
    La[i] = a_s[(size_t)base * 64 + i];
    Lf[i] = s_feat[(size_t)base * 64 + i];
  }
  __syncthreads();
  int d = tid & 63, g = tid >> 6;
  int n0 = base + g * 2;
  const float* A0 = La + g * 128;
  const float* A1 = A0 + 64;
  const float* F0 = Lf + g * 128;
  const float* F1 = F0 + 64;
  float a0 = 0, a1 = 0;
#pragma unroll 8
  for (int k = 0; k < 32; ++k) {
    uint32 w1 = W1[k * 64 + d], w2 = W2[k * 64 + d];
    int c = 2 * k;
    a0 += A0[c] * bfhi(w1) + A0[c + 1] * bflo(w1) + F0[c] * bfhi(w2) + F0[c + 1] * bflo(w2);
    a1 += A1[c] * bfhi(w1) + A1[c + 1] * bflo(w1) + F1[c] * bfhi(w2) + F1[c + 1] * bflo(w2);
  }
  sh[(size_t)n0 * 64 + d] = a0;
  sh[(size_t)(n0 + 1) * 64 + d] = a1;
  sh_bf[(size_t)n0 * 64 + d] = f2bf(a0);
  sh_bf[(size_t)(n0 + 1) * 64 + d] = f2bf(a1);
}

// ---------------- init_v: LDS-staged (bf16-packed weights, 4KB) ----------------
__global__ __launch_bounds__(256, 8) void k_init_v(
    const uint32* __restrict__ a_v, const float* __restrict__ Wv0,
    float* __restrict__ vh, uint32* __restrict__ vh_bf) {
  __shared__ uint32 W[32 * 32];  // 4KB: pair of rows
  int tid = threadIdx.x;
  for (int i = tid; i < 32 * 32; i += 256) {
    int k = i >> 5, d = i & 31;
    W[i] = packbf(Wv0[(2 * k) * 32 + d], Wv0[(2 * k + 1) * 32 + d]);
  }
  __syncthreads();
  int d = tid & 31, g = tid >> 5;
  int n = blockIdx.x * 8 + g;
  const uint2* av = (const uint2*)a_v + ((size_t)n << 6);
  float x = 0, y = 0, z = 0;
#pragma unroll 8
  for (int k = 0; k < 32; ++k) {
    uint32 w = W[k * 32 + d];
    uint2 e0 = av[2 * k], e1 = av[2 * k + 1];
    float w0 = bfhi(w), w1 = bflo(w);
    x += bfhi(e0.x) * w0 + bfhi(e1.x) * w1;
    y += bflo(e0.x) * w0 + bflo(e1.x) * w1;
    z += bfhi(e0.y) * w0 + bfhi(e1.y) * w1;
  }
  *(float4*)(vh + ((size_t)n << 7) + (d << 2)) = make_float4(x, y, z, 0.f);
  *(uint2*)(vh_bf + ((size_t)n << 6) + (d << 1)) = make_uint2(packbf(x, y), packbf(z, 0.f));
}

// ---------------- mix_s: LDS-staged (bf16-packed weights, 23KB) ----------------
__global__ __launch_bounds__(256, 6) void k_mix_s(
    const float* __restrict__ a_s, const float* __restrict__ sh_in,
    const float* __restrict__ Wmix_s, const float* __restrict__ Wself_s,
    const float* __restrict__ nsw, const float* __restrict__ skw,
    const float* __restrict__ skb, const float* __restrict__ cnoise,
    float* __restrict__ sh_out, ushort16* __restrict__ sh_bf_out) {
  __shared__ uint32 Wm[48 * 64];   // 12KB: rows (2k,2k+1) packed
  __shared__ uint32 Wsf[32 * 64];  // 8KB (scale folded in)
  __shared__ float La[8 * 96];     // 3KB
  int tid = threadIdx.x;
  float cn = cnoise[0];
  for (int i = tid; i < 48 * 64; i += 256) {
    int k = i >> 6, d = i & 63;
    Wm[i] = packbf(Wmix_s[(2 * k) * 64 + d], Wmix_s[(2 * k + 1) * 64 + d]);
  }
  for (int i = tid; i < 32 * 64; i += 256) {
    int k = i >> 6, d = i & 63;
    float sc0 = 1.f + cn * nsw[2 * k];
    float sc1 = 1.f + cn * nsw[2 * k + 1];
    Wsf[i] = packbf(Wself_s[(2 * k) * 64 + d] * sc0, Wself_s[(2 * k + 1) * 64 + d] * sc1);
  }
  int base = blockIdx.x * 8;
  for (int i = tid; i < 8 * 96; i += 256) La[i] = a_s[(size_t)base * 96 + i];
  __syncthreads();
  int d = tid & 63, g = tid >> 6;
  int n0 = base + g * 2;
  const float* A0 = La + (g * 2) * 96;
  const float* A1 = A0 + 96;
  const float* s0p = sh_in + (size_t)n0 * 64;
  const float* s1p = s0p + 64;
  float acc0 = 0, acc1 = 0;
#pragma unroll 8
  for (int k = 0; k < 48; ++k) {
    uint32 w = Wm[k * 64 + d];
    int c = 2 * k;
    float wh = bfhi(w), wl = bflo(w);
    acc0 += A0[c] * wh + A0[c + 1] * wl;
    acc1 += A1[c] * wh + A1[c + 1] * wl;
  }
#pragma unroll 8
  for (int k = 0; k < 32; ++k) {
    uint32 w = Wsf[k * 64 + d];
    int c = 2 * k;
    float wh = bfhi(w), wl = bflo(w);
    acc0 += s0p[c] * wh + s0p[c + 1] * wl;
    acc1 += s1p[c] * wh + s1p[c + 1] * wl;
  }
  float g1 = sigmoidf_(skb[d] + cn * skw[d]);
  float g2 = sigmoidf_(skb[64 + d] + cn * skw[64 + d]);
  float o0 = g1 * s0p[d] + g2 * acc0;
  float o1 = g1 * s1p[d] + g2 * acc1;
  sh_out[(size_t)n0 * 64 + d] = o0;
  sh_out[(size_t)(n0 + 1) * 64 + d] = o1;
  sh_bf_out[(size_t)n0 * 64 + d] = f2bf(o0);
  sh_bf_out[(size_t)(n0 + 1) * 64 + d] = f2bf(o1);
}

// ---------------- mix_v: LDS-staged (+ optional fused output) ----------------
__global__ __launch_bounds__(256, 8) void k_mix_v(
    const uint32* __restrict__ a_v, const float* __restrict__ vh_in,
    const float* __restrict__ Wmix_v, const float* __restrict__ Wself_v,
    const float* __restrict__ nsw, const float* __restrict__ skw,
    const float* __restrict__ skb, const float* __restrict__ cnoise,
    float* __restrict__ vh_out, uint32* __restrict__ vh_bf_out,
    const float* __restrict__ w_out, const float* __restrict__ gain,
    float* __restrict__ out, int doOut) {
  __shared__ uint32 Wm[64 * 32];   // 8KB
  __shared__ uint32 Wsf[16 * 32];  // 2KB (scale folded in)
  int tid = threadIdx.x;
  float cn = cnoise[0];
  for (int i = tid; i < 64 * 32; i += 256) {
    int k = i >> 5, d = i & 31;
    Wm[i] = packbf(Wmix_v[(2 * k) * 32 + d], Wmix_v[(2 * k + 1) * 32 + d]);
  }
  for (int i = tid; i < 16 * 32; i += 256) {
    int k = i >> 5, d = i & 31;
    float sc0 = 1.f + cn * nsw[64 + 2 * k];
    float sc1 = 1.f + cn * nsw[64 + 2 * k + 1];
    Wsf[i] = packbf(Wself_v[(2 * k) * 32 + d] * sc0, Wself_v[(2 * k + 1) * 32 + d] * sc1);
  }
  __syncthreads();
  int d = tid & 31, g = tid >> 5;
  int n = blockIdx.x * 8 + g;
  const uint2* av = (const uint2*)a_v + ((size_t)n << 7);
  const float4* vr = (const float4*)(vh_in + ((size_t)n << 7));
  float x = 0, y = 0, z = 0;
#pragma unroll 8
  for (int k = 0; k < 64; ++k) {
    uint32 w = Wm[k * 32 + d];
    uint2 e0 = av[2 * k], e1 = av[2 * k + 1];
    float w0 = bfhi(w), w1 = bflo(w);
    x += bfhi(e0.x) * w0 + bfhi(e1.x) * w1;
    y += bflo(e0.x) * w0 + bflo(e1.x) * w1;
    z += bfhi(e0.y) * w0 + bfhi(e1.y) * w1;
  }
#pragma unroll 8
  for (int k = 0; k < 16; ++k) {
    uint32 w = Wsf[k * 32 + d];
    float4 e0 = vr[2 * k], e1 = vr[2 * k + 1];
    float w0 = bfhi(w), w1 = bflo(w);
    x += e0.x * w0 + e1.x * w1;
    y += e0.y * w0 + e1.y * w1;
    z += e0.z * w0 + e1.z * w1;
  }
  float g3 = sigmoidf_(skb[128 + d] + cn * skw[128 + d]);
  float g4 = sigmoidf_(skb[160 + d] + cn * skw[160 + d]);
  float4 vi = vr[d];
  float ox = g3 * vi.x + g4 * x;
  float oy = g3 * vi.y + g4 * y;
  float oz = g3 * vi.z + g4 * z;
  *(float4*)(vh_out + ((size_t)n << 7) + (d << 2)) = make_float4(ox, oy, oz, 0.f);
  *(uint2*)(vh_bf_out + ((size_t)n << 6) + (d << 1)) = make_uint2(packbf(ox, oy), packbf(oz, 0.f));
  if (doOut) {
    float wv = w_out[d];
    float rx = wv * ox, ry = wv * oy, rz = wv * oz;
#pragma unroll
    for (int m = 16; m > 0; m >>= 1) {
      rx += __shfl_xor(rx, m, 32);
      ry += __shfl_xor(ry, m, 32);
      rz += __shfl_xor(rz, m, 32);
    }
    if (d == 0) {
      float gn = gain[0];
      float* op = out + (size_t)n * 3;
      op[0] = rx * gn; op[1] = ry * gn; op[2] = rz * gn;
    }
  }
}

extern "C" void kernel_launch(void* const* d_in, const int* in_sizes, int n_in,
                              void* d_out, int out_size, void* d_ws, size_t ws_size,
                              hipStream_t stream) {
  (void)in_sizes; (void)n_in; (void)out_size; (void)ws_size;
  const float* pos     = (const float*)d_in[0];
  const float* cn      = (const float*)d_in[1];
  const int*   types   = (const int*)d_in[2];
  const int*   rad     = (const int*)d_in[3];
  const int*   bon     = (const int*)d_in[4];
  const float* atom_tab= (const float*)d_in[5];
  const float* bond_tab= (const float*)d_in[6];
  const float* ns0_w   = (const float*)d_in[7];
  const float* We0     = (const float*)d_in[8];
  const float* We1     = (const float*)d_in[9];
  const float* Wself0  = (const float*)d_in[10];
  const float* Ws0     = (const float*)d_in[11];
  const float* Wv0     = (const float*)d_in[12];
  const float* ns_w    = (const float*)d_in[13];
  const float* We_ss   = (const float*)d_in[14];
  const float* We_vs   = (const float*)d_in[15];
  const float* We_sv   = (const float*)d_in[16];
  const float* We_vv   = (const float*)d_in[17];
  const float* We_vx   = (const float*)d_in[18];
  const float* Wmix_s  = (const float*)d_in[19];
  const float* Wmix_v  = (const float*)d_in[20];
  const float* Wself_s = (const float*)d_in[21];
  const float* Wself_v = (const float*)d_in[22];
  const float* skip_w  = (const float*)d_in[23];
  const float* skip_b  = (const float*)d_in[24];
  const float* w_out   = (const float*)d_in[25];
  const float* gain    = (const float*)d_in[26];

  char* ws = (char*)d_ws;
  size_t o = 0;
  auto alloc = [&](size_t bytes) -> void* {
    void* p = ws + o;
    o += (bytes + 255) & ~(size_t)255;
    return p;
  };
  float* s_feat  = (float*)alloc((size_t)NA * 64 * 4);
  ushort16* s_bf = (ushort16*)alloc((size_t)NA * 64 * 2);
  float* a_s     = (float*)alloc((size_t)NA * 96 * 4);
  uint32* a_v    = (uint32*)alloc((size_t)NA * 256 * 4);  // [n][128] uint2; agg0 uses [n][64] uint2
  float* sh0     = (float*)alloc((size_t)NA * 64 * 4);
  float* sh1     = (float*)alloc((size_t)NA * 64 * 4);
  ushort16* shbf0= (ushort16*)alloc((size_t)NA * 64 * 2);
  ushort16* shbf1= (ushort16*)alloc((size_t)NA * 64 * 2);
  float* vh0     = (float*)alloc((size_t)NA * 128 * 4);  // [n][32][4]
  float* vh1     = (float*)alloc((size_t)NA * 128 * 4);
  uint32* vhbf0  = (uint32*)alloc((size_t)NA * 64 * 4);  // [n][32][2] uints
  uint32* vhbf1  = (uint32*)alloc((size_t)NA * 64 * 4);
  int* count     = (int*)alloc((size_t)NA * 4);
  int* partial   = (int*)alloc((size_t)64 * 4);
  int* offsets   = (int*)alloc((size_t)(NA + 1) * 4);
  int* cursor    = (int*)alloc((size_t)NA * 4);
  int* sorted    = (int*)alloc((size_t)ET * 4);
  float* rec8    = (float*)alloc((size_t)ET * 32);
  uint32* T0     = (uint32*)alloc((size_t)T0U * 4);
  uint32* TL     = (uint32*)alloc((size_t)2 * TLU * 4);
  float* shb[2]  = {sh0, sh1};
  ushort16* shbf[2] = {shbf0, shbf1};
  float* vhb[2]  = {vh0, vh1};
  uint32* vhbf[2]= {vhbf0, vhbf1};

  // CSR build + tables
  hipMemsetAsync(count, 0, (size_t)NA * 4, stream);
  k_hist<<<ET / 256, 256, 0, stream>>>(rad, bon, count);
  k_scan1<<<64, 256, 0, stream>>>(count, partial);
  k_scan2<<<1, 1, 0, stream>>>(partial);
  k_scan3<<<64, 256, 0, stream>>>(count, partial, offsets, cursor);
  k_fill_embed<<<ET / 256 + NA * 64 / 256, 256, 0, stream>>>(
      rad, bon, cursor, sorted, atom_tab, types, ns0_w, cn, s_feat, s_bf);
  k_reorder<<<ET / 256, 256, 0, stream>>>(sorted, rad, bon, pos, rec8);
  k_build<<<dim3(BINS, 3, 2), 64, 0, stream>>>(We0, We1, We_ss, We_vs, We_sv, We_vv, We_vx,
                                               bond_tab, T0, TL);

  k_agg0<<<NA / 4, 256, 0, stream>>>(offsets, rec8, T0, s_bf, a_s, a_v);
  k_init_s<<<NA / 8, 256, 0, stream>>>(a_s, s_feat, Ws0, Wself0, shb[0], shbf[0]);
  k_init_v<<<NA / 8, 256, 0, stream>>>(a_v, Wv0, vhb[0], vhbf[0]);

  for (int l = 0; l < 2; ++l) {
    int bin = l & 1, bout = 1 - bin;
    k_agg_layer<<<NA / 4, 256, 0, stream>>>(
        cn, ns_w + l * 96, offsets, rec8, TL + (size_t)l * TLU, shbf[bin], vhbf[bin], a_s, a_v);
    k_mix_s<<<NA / 8, 256, 0, stream>>>(
        a_s, shb[bin], Wmix_s + l * 96 * 64, Wself_s + l * 64 * 64,
        ns_w + l * 96, skip_w + l * 192, skip_b + l * 192, cn, shb[bout], shbf[bout]);
    k_mix_v<<<NA / 8, 256, 0, stream>>>(
        a_v, vhb[bin], Wmix_v + l * 128 * 32, Wself_v + l * 32 * 32,
        ns_w + l * 96, skip_w + l * 192, skip_b + l * 192, cn, vhb[bout], vhbf[bout],
        w_out, gain, (float*)d_out, l == 1);
  }
}

// Round 19
// 474.106 us; speedup vs baseline: 1.0731x; 1.0191x over previous
//
#include <hip/hip_runtime.h>
#include <math.h>

#define NA 16384
#define ER 524288
#define EB 32768
#define ET 557056
#define INV_NORM 0.17149858514250882f   // 1/sqrt((ER+EB)/NA) = 1/sqrt(34)
#define SQRT3 1.7320508075688772f
#define RB_STEP (1.5f/9.0f)
#define BINS 512
#define DMAX 2.5f
#define INV_H ((float)BINS / DMAX)
#define T0U (2 * BINS * 128)    // agg0 table: [2][BINS][64][2] uints
#define TLU (2 * BINS * 256)    // layer table: [2][BINS][64][4] uints

typedef unsigned int uint32;
typedef unsigned short ushort16;
typedef unsigned int vu4 __attribute__((ext_vector_type(4)));

__device__ __forceinline__ float sigmoidf_(float x) { return 1.f / (1.f + __expf(-x)); }

__device__ __forceinline__ ushort16 f2bf(float x) {
  uint32 u = __float_as_uint(x);
  u = u + 0x7FFFu + ((u >> 16) & 1u);
  return (ushort16)(u >> 16);
}
__device__ __forceinline__ uint32 packbf(float hi, float lo) {
  return ((uint32)f2bf(hi) << 16) | (uint32)f2bf(lo);
}
__device__ __forceinline__ float bfhi(uint32 u) { return __uint_as_float(u & 0xFFFF0000u); }
__device__ __forceinline__ float bflo(uint32 u) { return __uint_as_float(u << 16); }

// nontemporal helpers — ONLY for the rec stream (written once, streamed; must not
// evict the gather working set). Producer->consumer intermediates use cached stores.
__device__ __forceinline__ uint4 ntlu4(const uint32* p) {
  vu4 v = __builtin_nontemporal_load((const vu4*)p);
  return make_uint4(v.x, v.y, v.z, v.w);
}
__device__ __forceinline__ void ntsu4(uint32* p, uint32 a, uint32 b, uint32 c, uint32 d) {
  vu4 v; v.x = a; v.y = b; v.z = c; v.w = d;
  __builtin_nontemporal_store(v, (vu4*)p);
}

// ---------------- CSR build ----------------
__global__ void k_hist(const int* __restrict__ rad, const int* __restrict__ bon, int* __restrict__ count) {
  int e = blockIdx.x * 256 + threadIdx.x;
  int d = (e < ER) ? rad[ER + e] : bon[EB + (e - ER)];
  atomicAdd(&count[d], 1);
}

// single-block scan (R11 structure): offsets + cursor in one launch
__global__ void k_scan(int* __restrict__ count, int* __restrict__ offsets, int* __restrict__ cursor) {
  __shared__ int part[256];
  int t = threadIdx.x;
  int base = t * 64;
  int s = 0;
  for (int j = 0; j < 64; ++j) s += count[base + j];
  part[t] = s;
  __syncthreads();
  for (int off = 1; off < 256; off <<= 1) {
    int v = (t >= off) ? part[t - off] : 0;
    __syncthreads();
    part[t] += v;
    __syncthreads();
  }
  int run = part[t] - s;  // exclusive prefix
  for (int j = 0; j < 64; ++j) {
    int c = count[base + j];
    offsets[base + j] = run;
    cursor[base + j] = run;
    run += c;
  }
  if (t == 255) offsets[NA] = run;
}

// ---------------- fused: slot-scatter (4B) | embedding ----------------
__global__ void k_fill_embed(const int* __restrict__ rad, const int* __restrict__ bon,
                             int* __restrict__ cursor, int* __restrict__ sorted,
                             const float* __restrict__ atom_tab, const int* __restrict__ types,
                             const float* __restrict__ ns0_w, const float* __restrict__ cnoise,
                             float* __restrict__ s_feat, ushort16* __restrict__ s_bf) {
  if (blockIdx.x < ET / 256) {
    int e = blockIdx.x * 256 + threadIdx.x;
    int d = (e < ER) ? rad[ER + e] : bon[EB + (e - ER)];
    int slot = atomicAdd(&cursor[d], 1);
    sorted[slot] = e;
  } else {
    int tid = (blockIdx.x - ET / 256) * 256 + threadIdx.x;
    int n = tid >> 6, c = tid & 63;
    float cn = cnoise[0];
    float v = atom_tab[types[n] * 64 + c] * (1.f + cn * ns0_w[c]);
    s_feat[tid] = v;
    s_bf[tid] = f2bf(v);
  }
}

// ---------------- merged: reorder (coalesced 16B rec write) | table build ----------------
// record[idx] (16B uint4): {src, packbf(Y0,Y1), packbf(Y2,frac), qoffL}; agg0 offset = qoffL>>1
__global__ void k_reorder_build(
    const int* __restrict__ sorted, const int* __restrict__ rad, const int* __restrict__ bon,
    const float* __restrict__ pos, uint32* __restrict__ rec4,
    const float* __restrict__ We0, const float* __restrict__ We1,
    const float* __restrict__ We_ss, const float* __restrict__ We_vs,
    const float* __restrict__ We_sv, const float* __restrict__ We_vv,
    const float* __restrict__ We_vx, const float* __restrict__ bond_tab,
    uint32* __restrict__ T0, uint32* __restrict__ TL) {
  if (blockIdx.x < ET / 256) {
    int idx = blockIdx.x * 256 + threadIdx.x;
    int e = sorted[idx];
    int src, dst, v;
    if (e < ER) { src = rad[e]; dst = rad[ER + e]; v = 0; }
    else        { src = bon[e - ER]; dst = bon[EB + e - ER]; v = 1; }
    float dx = pos[src * 3] - pos[dst * 3];
    float dy = pos[src * 3 + 1] - pos[dst * 3 + 1];
    float dz = pos[src * 3 + 2] - pos[dst * 3 + 2];
    float dist = sqrtf(dx * dx + dy * dy + dz * dz + 1e-12f);
    float inv = 1.f / dist;
    float fq = fminf(dist * INV_H, BINS - 1.001f);
    int q = (int)fq;
    float frac = fq - (float)q;
    int qoffL = (v * BINS + q) << 8;
    ntsu4(rec4 + (size_t)idx * 4, (uint32)src,
          packbf(SQRT3 * dx * inv, SQRT3 * dy * inv),
          packbf(SQRT3 * dz * inv, frac), (uint32)qoffL);
  } else {
    int flat = (blockIdx.x - ET / 256) * 256 + threadIdx.x;  // < 3072*64
    int c = flat & 63;
    int rest = flat >> 6;          // 0..3071
    int q = rest & (BINS - 1);
    int tv = rest >> 9;            // 0..5
    int t = tv % 3, v = tv / 3;
    float d0 = q * (DMAX / BINS), d1 = (q + 1) * (DMAX / BINS);
    float rb0[8], rb1[8];
#pragma unroll
    for (int k = 0; k < 8; ++k) {
      float f0 = (d0 - (k + 1) * RB_STEP) * (1.f / RB_STEP);
      float f1 = (d1 - (k + 1) * RB_STEP) * (1.f / RB_STEP);
      rb0[k] = 1.12f * __expf(-f0 * f0);
      rb1[k] = 1.12f * __expf(-f1 * f1);
    }
    if (t == 0) {
      float ba = 0, bb = 0, a0 = 0, a1 = 0, b0 = 0, b1 = 0;
#pragma unroll
      for (int k = 0; k < 8; ++k) {
        float bt = bond_tab[v * 8 + k];
        float av_lo = We0[k * 64 + c], av_hi = We0[(8 + k) * 64 + c];
        float bv_lo = We1[k * 64 + c], bv_hi = We1[(8 + k) * 64 + c];
        ba += bt * av_lo; bb += bt * bv_lo;
        a0 += rb0[k] * av_hi; a1 += rb1[k] * av_hi;
        b0 += rb0[k] * bv_hi; b1 += rb1[k] * bv_hi;
      }
      uint32* o = T0 + (((size_t)v * BINS + q) << 7) + c * 2;
      o[0] = packbf(ba + a0, a1 - a0);
      o[1] = packbf(bb + b0, b1 - b0);
    } else {
      int l = t - 1;
      const float* Wss = We_ss + l * 1024;
      const float* Wsv = We_sv + l * 1024;
      const float* WA = (c < 32) ? (We_vs + l * 512) : (We_vx + l * 512);
      const float* WB = (c < 32) ? (We_vv + l * 512) : nullptr;
      int cu = c & 31;
      float sa = 0, sb = 0, s0 = 0, s1 = 0, t0 = 0, t1 = 0;
      float ua = 0, ub = 0, u0 = 0, u1 = 0, w0 = 0, w1 = 0;
#pragma unroll
      for (int k = 0; k < 8; ++k) {
        float bt = bond_tab[v * 8 + k];
        float ss_lo = Wss[k * 64 + c], ss_hi = Wss[(8 + k) * 64 + c];
        float sv_lo = Wsv[k * 64 + c], sv_hi = Wsv[(8 + k) * 64 + c];
        sa += bt * ss_lo; sb += bt * sv_lo;
        s0 += rb0[k] * ss_hi; s1 += rb1[k] * ss_hi;
        t0 += rb0[k] * sv_hi; t1 += rb1[k] * sv_hi;
        float a_lo = WA[k * 32 + cu], a_hi = WA[(8 + k) * 32 + cu];
        ua += bt * a_lo;
        u0 += rb0[k] * a_hi; u1 += rb1[k] * a_hi;
        if (WB) {
          float b_lo = WB[k * 32 + cu], b_hi = WB[(8 + k) * 32 + cu];
          ub += bt * b_lo;
          w0 += rb0[k] * b_hi; w1 += rb1[k] * b_hi;
        }
      }
      uint32* o = TL + (size_t)l * TLU + (((size_t)v * BINS + q) << 8) + c * 4;
      o[0] = packbf(sa + s0, s1 - s0);
      o[1] = packbf(sb + t0, t1 - t0);
      o[2] = packbf(ua + u0, u1 - u0);
      o[3] = WB ? packbf(ub + w0, w1 - w0) : 0u;
    }
  }
}

// ---------------- initial aggregation (3-stage pipeline, 16B nt rec) ----------------
// a_v layout: [n][64] uint2 (bf16 x|y, z|0)
__global__ __launch_bounds__(256, 8) void k_agg0(
    const int* __restrict__ offsets, const uint32* __restrict__ rec4,
    const uint32* __restrict__ T0, const ushort16* __restrict__ s_bf,
    float* __restrict__ a_s, uint32* __restrict__ a_v) {
  int lane = threadIdx.x & 63;
  int n = blockIdx.x * 4 + (threadIdx.x >> 6);
  float acc = 0, a0 = 0, a1 = 0, a2 = 0;
  int beg = __builtin_amdgcn_readfirstlane(offsets[n]);
  int end = __builtin_amdgcn_readfirstlane(offsets[n + 1]);
  if (beg < end) {
    int last = end - 1;
    int e1 = (beg + 1 < end) ? beg + 1 : last;
    int e2 = (beg + 2 < end) ? beg + 2 : last;
    uint4 r0 = ntlu4(rec4 + (size_t)beg * 4);
    uint4 r1 = ntlu4(rec4 + (size_t)e1 * 4);
    uint4 r2 = ntlu4(rec4 + (size_t)e2 * 4);
    uint2 t0 = *(const uint2*)(T0 + (r0.w >> 1) + (lane << 1));
    ushort16 s0 = s_bf[((size_t)r0.x << 6) + lane];
    uint2 t1 = *(const uint2*)(T0 + (r1.w >> 1) + (lane << 1));
    ushort16 s1 = s_bf[((size_t)r1.x << 6) + lane];
#pragma unroll 3
    for (int idx = beg; idx < end; ++idx) {
      uint2 t2 = *(const uint2*)(T0 + (r2.w >> 1) + (lane << 1));
      ushort16 s2 = s_bf[((size_t)r2.x << 6) + lane];
      int e3 = (idx + 3 < end) ? idx + 3 : last;
      uint4 r3 = ntlu4(rec4 + (size_t)e3 * 4);
      float frac = bflo(r0.z);
      float w0 = fmaf(frac, bflo(t0.x), bfhi(t0.x));
      float w1 = fmaf(frac, bflo(t0.y), bfhi(t0.y));
      float sv = __uint_as_float((uint32)s0 << 16);
      acc += w0 * sv;
      float t = w1 * sv;
      a0 += t * bfhi(r0.y); a1 += t * bflo(r0.y); a2 += t * bfhi(r0.z);
      r0 = r1; r1 = r2; r2 = r3;
      t0 = t1; s0 = s1; t1 = t2; s1 = s2;
    }
  }
  a_s[n * 64 + lane] = acc * INV_NORM;
  *(uint2*)(a_v + ((size_t)n << 7) + (lane << 1)) =
      make_uint2(packbf(a0 * INV_NORM, a1 * INV_NORM), packbf(a2 * INV_NORM, 0.f));
}

// ---------------- layer aggregation (3-stage pipeline, 16B nt rec) ----------------
// a_v layout: [n][128] uint2
__global__ __launch_bounds__(256, 8) void k_agg_layer(
    const float* __restrict__ cnoise, const float* __restrict__ nsw,
    const int* __restrict__ offsets, const uint32* __restrict__ rec4,
    const uint32* __restrict__ TL, const ushort16* __restrict__ sh_bf,
    const uint32* __restrict__ vh_bf,
    float* __restrict__ a_s, uint32* __restrict__ a_v) {
  int lane = threadIdx.x & 63;
  int n = blockIdx.x * 4 + (threadIdx.x >> 6);
  int vc = lane & 31;
  bool low = lane < 32;
  float cn = cnoise[0];
  float scale_s = 1.f + cn * nsw[lane];
  float scale_v = 1.f + cn * nsw[64 + vc];

  float ms = 0;
  float av0 = 0, av1 = 0, av2 = 0;
  float ms2 = 0;
  float b0 = 0, b1 = 0, b2 = 0;
  int beg = __builtin_amdgcn_readfirstlane(offsets[n]);
  int end = __builtin_amdgcn_readfirstlane(offsets[n + 1]);
  if (beg < end) {
    int last = end - 1;
    int e1 = (beg + 1 < end) ? beg + 1 : last;
    int e2 = (beg + 2 < end) ? beg + 2 : last;
    uint4 r0 = ntlu4(rec4 + (size_t)beg * 4);
    uint4 r1 = ntlu4(rec4 + (size_t)e1 * 4);
    uint4 r2 = ntlu4(rec4 + (size_t)e2 * 4);
    uint4 t0 = *(const uint4*)(TL + r0.w + (lane << 2));
    ushort16 s0 = sh_bf[((size_t)r0.x << 6) + lane];
    uint2 v0 = *(const uint2*)(vh_bf + ((size_t)r0.x << 6) + (vc << 1));
    uint4 t1 = *(const uint4*)(TL + r1.w + (lane << 2));
    ushort16 s1 = sh_bf[((size_t)r1.x << 6) + lane];
    uint2 v1 = *(const uint2*)(vh_bf + ((size_t)r1.x << 6) + (vc << 1));
#pragma unroll 3
    for (int idx = beg; idx < end; ++idx) {
      uint4 t2 = *(const uint4*)(TL + r2.w + (lane << 2));
      ushort16 s2 = sh_bf[((size_t)r2.x << 6) + lane];
      uint2 v2 = *(const uint2*)(vh_bf + ((size_t)r2.x << 6) + (vc << 1));
      int e3 = (idx + 3 < end) ? idx + 3 : last;
      uint4 r3 = ntlu4(rec4 + (size_t)e3 * 4);
      float frac = bflo(r0.z);
      float y0 = bfhi(r0.y), y1 = bflo(r0.y), y2 = bfhi(r0.z);
      float wS  = fmaf(frac, bflo(t0.x), bfhi(t0.x));
      float wSV = fmaf(frac, bflo(t0.y), bfhi(t0.y));
      float wA  = fmaf(frac, bflo(t0.z), bfhi(t0.z));
      float wB  = fmaf(frac, bflo(t0.w), bfhi(t0.w));
      float ss = __uint_as_float((uint32)s0 << 16);
      float vx = bfhi(v0.x), vy = bflo(v0.x), vz = bfhi(v0.y);
      ms += wS * ss;
      float t = wSV * ss;
      av0 += t * y0; av1 += t * y1; av2 += t * y2;
      float vdot = vx * y0 + vy * y1 + vz * y2;
      ms2 += wA * vdot;  // garbage on high lanes, never written
      float cx = vy * y2 - vz * y1;
      float cy = vz * y0 - vx * y2;
      float cz = vx * y1 - vy * y0;
      float m0 = low ? vx : cx;
      float m1 = low ? vy : cy;
      float m2 = low ? vz : cz;
      float wM = low ? wB : wA;
      b0 += wM * m0; b1 += wM * m1; b2 += wM * m2;
      r0 = r1; r1 = r2; r2 = r3;
      t0 = t1; s0 = s1; v0 = v1; t1 = t2; s1 = s2; v1 = v2;
    }
  }
  float fs = scale_s * INV_NORM;
  float fv = scale_v * INV_NORM;
  a_s[n * 96 + lane] = ms * fs;
  uint32* avn = a_v + ((size_t)n << 8);
  *(uint2*)(avn + (lane << 1)) = make_uint2(packbf(av0 * fs, av1 * fs), packbf(av2 * fs, 0.f));
  if (low) {
    a_s[n * 96 + 64 + vc] = ms2 * fv;
    *(uint2*)(avn + ((64 + vc) << 1)) = make_uint2(packbf(b0 * fv, b1 * fv), packbf(b2 * fv, 0.f));
  } else {
    *(uint2*)(avn + ((96 + vc) << 1)) = make_uint2(packbf(b0 * fv, b1 * fv), packbf(b2 * fv, 0.f));
  }
}

// ---------------- init_s: LDS-staged (bf16-packed weights, 20KB) ----------------
__global__ __launch_bounds__(256, 8) void k_init_s(
    const float* __restrict__ a_s, const float* __restrict__ s_feat,
    const float* __restrict__ Ws0, const float* __restrict__ Wself0,
    float* __restrict__ sh, ushort16* __restrict__ sh_bf) {
  __shared__ uint32 W1[32 * 64];
  __shared__ uint32 W2[32 * 64];
  __shared__ float La[8 * 64];
  __shared__ float Lf[8 * 64];
  int tid = threadIdx.x;
  for (int i = tid; i < 32 * 64; i += 256) {
    int k = i >> 6, d = i & 63;
    W1[i] = packbf(Ws0[(2 * k) * 64 + d], Ws0[(2 * k + 1) * 64 + d]);
    W2[i] = packbf(Wself0[(2 * k) * 64 + d], Wself0[(2 * k + 1) * 64 + d]);
  }
  int base = blockIdx.x * 8;
  for (int i = tid; i < 512; i += 256) {
    La[i] = a_s[(size_t)base * 64 + i];
    Lf[i] = s_feat[(size_t)base * 64 + i];
  }
  __syncthreads();
  int d = tid & 63, g = tid >> 6;
  int n0 = base + g * 2;
  const float* A0 = La + g * 128;
  const float* A1 = A0 + 64;
  const float* F0 = Lf + g * 128;
  const float* F1 = F0 + 64;
  float a0 = 0, a1 = 0;
#pragma unroll 8
  for (int k = 0; k < 32; ++k) {
    uint32 w1 = W1[k * 64 + d], w2 = W2[k * 64 + d];
    int c = 2 * k;
    a0 += A0[c] * bfhi(w1) + A0[c + 1] * bflo(w1) + F0[c] * bfhi(w2) + F0[c + 1] * bflo(w2);
    a1 += A1[c] * bfhi(w1) + A1[c + 1] * bflo(w1) + F1[c] * bfhi(w2) + F1[c + 1] * bflo(w2);
  }
  sh[(size_t)n0 * 64 + d] = a0;
  sh[(size_t)(n0 + 1) * 64 + d] = a1;
  sh_bf[(size_t)n0 * 64 + d] = f2bf(a0);
  sh_bf[(size_t)(n0 + 1) * 64 + d] = f2bf(a1);
}

// ---------------- init_v: LDS-staged (bf16-packed weights, 4KB) ----------------
__global__ __launch_bounds__(256, 8) void k_init_v(
    const uint32* __restrict__ a_v, const float* __restrict__ Wv0,
    float* __restrict__ vh, uint32* __restrict__ vh_bf) {
  __shared__ uint32 W[32 * 32];
  int tid = threadIdx.x;
  for (int i = tid; i < 32 * 32; i += 256) {
    int k = i >> 5, d = i & 31;
    W[i] = packbf(Wv0[(2 * k) * 32 + d], Wv0[(2 * k + 1) * 32 + d]);
  }
  __syncthreads();
  int d = tid & 31, g = tid >> 5;
  int n = blockIdx.x * 8 + g;
  const uint2* av = (const uint2*)a_v + ((size_t)n << 6);
  float x = 0, y = 0, z = 0;
#pragma unroll 8
  for (int k = 0; k < 32; ++k) {
    uint32 w = W[k * 32 + d];
    uint2 e0 = av[2 * k], e1 = av[2 * k + 1];
    float w0 = bfhi(w), w1 = bflo(w);
    x += bfhi(e0.x) * w0 + bfhi(e1.x) * w1;
    y += bflo(e0.x) * w0 + bflo(e1.x) * w1;
    z += bfhi(e0.y) * w0 + bfhi(e1.y) * w1;
  }
  *(float4*)(vh + ((size_t)n << 7) + (d << 2)) = make_float4(x, y, z, 0.f);
  *(uint2*)(vh_bf + ((size_t)n << 6) + (d << 1)) = make_uint2(packbf(x, y), packbf(z, 0.f));
}

// ---------------- mix_s: LDS-staged (bf16-packed weights, 23KB) ----------------
__global__ __launch_bounds__(256, 6) void k_mix_s(
    const float* __restrict__ a_s, const float* __restrict__ sh_in,
    const float* __restrict__ Wmix_s, const float* __restrict__ Wself_s,
    const float* __restrict__ nsw, const float* __restrict__ skw,
    const float* __restrict__ skb, const float* __restrict__ cnoise,
    float* __restrict__ sh_out, ushort16* __restrict__ sh_bf_out) {
  __shared__ uint32 Wm[48 * 64];
  __shared__ uint32 Wsf[32 * 64];
  __shared__ float La[8 * 96];
  int tid = threadIdx.x;
  float cn = cnoise[0];
  for (int i = tid; i < 48 * 64; i += 256) {
    int k = i >> 6, d = i & 63;
    Wm[i] = packbf(Wmix_s[(2 * k) * 64 + d], Wmix_s[(2 * k + 1) * 64 + d]);
  }
  for (int i = tid; i < 32 * 64; i += 256) {
    int k = i >> 6, d = i & 63;
    float sc0 = 1.f + cn * nsw[2 * k];
    float sc1 = 1.f + cn * nsw[2 * k + 1];
    Wsf[i] = packbf(Wself_s[(2 * k) * 64 + d] * sc0, Wself_s[(2 * k + 1) * 64 + d] * sc1);
  }
  int base = blockIdx.x * 8;
  for (int i = tid; i < 8 * 96; i += 256) La[i] = a_s[(size_t)base * 96 + i];
  __syncthreads();
  int d = tid & 63, g = tid >> 6;
  int n0 = base + g * 2;
  const float* A0 = La + (g * 2) * 96;
  const float* A1 = A0 + 96;
  const float* s0p = sh_in + (size_t)n0 * 64;
  const float* s1p = s0p + 64;
  float acc0 = 0, acc1 = 0;
#pragma unroll 8
  for (int k = 0; k < 48; ++k) {
    uint32 w = Wm[k * 64 + d];
    int c = 2 * k;
    float wh = bfhi(w), wl = bflo(w);
    acc0 += A0[c] * wh + A0[c + 1] * wl;
    acc1 += A1[c] * wh + A1[c + 1] * wl;
  }
#pragma unroll 8
  for (int k = 0; k < 32; ++k) {
    uint32 w = Wsf[k * 64 + d];
    int c = 2 * k;
    float wh = bfhi(w), wl = bflo(w);
    acc0 += s0p[c] * wh + s0p[c + 1] * wl;
    acc1 += s1p[c] * wh + s1p[c + 1] * wl;
  }
  float g1 = sigmoidf_(skb[d] + cn * skw[d]);
  float g2 = sigmoidf_(skb[64 + d] + cn * skw[64 + d]);
  float o0 = g1 * s0p[d] + g2 * acc0;
  float o1 = g1 * s1p[d] + g2 * acc1;
  sh_out[(size_t)n0 * 64 + d] = o0;
  sh_out[(size_t)(n0 + 1) * 64 + d] = o1;
  sh_bf_out[(size_t)n0 * 64 + d] = f2bf(o0);
  sh_bf_out[(size_t)(n0 + 1) * 64 + d] = f2bf(o1);
}

// ---------------- mix_v: LDS-staged (+ optional fused output) ----------------
__global__ __launch_bounds__(256, 8) void k_mix_v(
    const uint32* __restrict__ a_v, const float* __restrict__ vh_in,
    const float* __restrict__ Wmix_v, const float* __restrict__ Wself_v,
    const float* __restrict__ nsw, const float* __restrict__ skw,
    const float* __restrict__ skb, const float* __restrict__ cnoise,
    float* __restrict__ vh_out, uint32* __restrict__ vh_bf_out,
    const float* __restrict__ w_out, const float* __restrict__ gain,
    float* __restrict__ out, int doOut) {
  __shared__ uint32 Wm[64 * 32];
  __shared__ uint32 Wsf[16 * 32];
  int tid = threadIdx.x;
  float cn = cnoise[0];
  for (int i = tid; i < 64 * 32; i += 256) {
    int k = i >> 5, d = i & 31;
    Wm[i] = packbf(Wmix_v[(2 * k) * 32 + d], Wmix_v[(2 * k + 1) * 32 + d]);
  }
  for (int i = tid; i < 16 * 32; i += 256) {
    int k = i >> 5, d = i & 31;
    float sc0 = 1.f + cn * nsw[64 + 2 * k];
    float sc1 = 1.f + cn * nsw[64 + 2 * k + 1];
    Wsf[i] = packbf(Wself_v[(2 * k) * 32 + d] * sc0, Wself_v[(2 * k + 1) * 32 + d] * sc1);
  }
  __syncthreads();
  int d = tid & 31, g = tid >> 5;
  int n = blockIdx.x * 8 + g;
  const uint2* av = (const uint2*)a_v + ((size_t)n << 7);
  const float4* vr = (const float4*)(vh_in + ((size_t)n << 7));
  float x = 0, y = 0, z = 0;
#pragma unroll 8
  for (int k = 0; k < 64; ++k) {
    uint32 w = Wm[k * 32 + d];
    uint2 e0 = av[2 * k], e1 = av[2 * k + 1];
    float w0 = bfhi(w), w1 = bflo(w);
    x += bfhi(e0.x) * w0 + bfhi(e1.x) * w1;
    y += bflo(e0.x) * w0 + bflo(e1.x) * w1;
    z += bfhi(e0.y) * w0 + bfhi(e1.y) * w1;
  }
#pragma unroll 8
  for (int k = 0; k < 16; ++k) {
    uint32 w = Wsf[k * 32 + d];
    float4 e0 = vr[2 * k], e1 = vr[2 * k + 1];
    float w0 = bfhi(w), w1 = bflo(w);
    x += e0.x * w0 + e1.x * w1;
    y += e0.y * w0 + e1.y * w1;
    z += e0.z * w0 + e1.z * w1;
  }
  float g3 = sigmoidf_(skb[128 + d] + cn * skw[128 + d]);
  float g4 = sigmoidf_(skb[160 + d] + cn * skw[160 + d]);
  float4 vi = vr[d];
  float ox = g3 * vi.x + g4 * x;
  float oy = g3 * vi.y + g4 * y;
  float oz = g3 * vi.z + g4 * z;
  *(float4*)(vh_out + ((size_t)n << 7) + (d << 2)) = make_float4(ox, oy, oz, 0.f);
  *(uint2*)(vh_bf_out + ((size_t)n << 6) + (d << 1)) = make_uint2(packbf(ox, oy), packbf(oz, 0.f));
  if (doOut) {
    float wv = w_out[d];
    float rx = wv * ox, ry = wv * oy, rz = wv * oz;
#pragma unroll
    for (int m = 16; m > 0; m >>= 1) {
      rx += __shfl_xor(rx, m, 32);
      ry += __shfl_xor(ry, m, 32);
      rz += __shfl_xor(rz, m, 32);
    }
    if (d == 0) {
      float gn = gain[0];
      float* op = out + (size_t)n * 3;
      op[0] = rx * gn; op[1] = ry * gn; op[2] = rz * gn;
    }
  }
}

extern "C" void kernel_launch(void* const* d_in, const int* in_sizes, int n_in,
                              void* d_out, int out_size, void* d_ws, size_t ws_size,
                              hipStream_t stream) {
  (void)in_sizes; (void)n_in; (void)out_size; (void)ws_size;
  const float* pos     = (const float*)d_in[0];
  const float* cn      = (const float*)d_in[1];
  const int*   types   = (const int*)d_in[2];
  const int*   rad     = (const int*)d_in[3];
  const int*   bon     = (const int*)d_in[4];
  const float* atom_tab= (const float*)d_in[5];
  const float* bond_tab= (const float*)d_in[6];
  const float* ns0_w   = (const float*)d_in[7];
  const float* We0     = (const float*)d_in[8];
  const float* We1     = (const float*)d_in[9];
  const float* Wself0  = (const float*)d_in[10];
  const float* Ws0     = (const float*)d_in[11];
  const float* Wv0     = (const float*)d_in[12];
  const float* ns_w    = (const float*)d_in[13];
  const float* We_ss   = (const float*)d_in[14];
  const float* We_vs   = (const float*)d_in[15];
  const float* We_sv   = (const float*)d_in[16];
  const float* We_vv   = (const float*)d_in[17];
  const float* We_vx   = (const float*)d_in[18];
  const float* Wmix_s  = (const float*)d_in[19];
  const float* Wmix_v  = (const float*)d_in[20];
  const float* Wself_s = (const float*)d_in[21];
  const float* Wself_v = (const float*)d_in[22];
  const float* skip_w  = (const float*)d_in[23];
  const float* skip_b  = (const float*)d_in[24];
  const float* w_out   = (const float*)d_in[25];
  const float* gain    = (const float*)d_in[26];

  char* ws = (char*)d_ws;
  size_t o = 0;
  auto alloc = [&](size_t bytes) -> void* {
    void* p = ws + o;
    o += (bytes + 255) & ~(size_t)255;
    return p;
  };
  float* s_feat  = (float*)alloc((size_t)NA * 64 * 4);
  ushort16* s_bf = (ushort16*)alloc((size_t)NA * 64 * 2);
  float* a_s     = (float*)alloc((size_t)NA * 96 * 4);
  uint32* a_v    = (uint32*)alloc((size_t)NA * 256 * 4);  // [n][128] uint2; agg0 uses [n][64] uint2
  float* sh0     = (float*)alloc((size_t)NA * 64 * 4);
  float* sh1     = (float*)alloc((size_t)NA * 64 * 4);
  ushort16* shbf0= (ushort16*)alloc((size_t)NA * 64 * 2);
  ushort16* shbf1= (ushort16*)alloc((size_t)NA * 64 * 2);
  float* vh0     = (float*)alloc((size_t)NA * 128 * 4);  // [n][32][4]
  float* vh1     = (float*)alloc((size_t)NA * 128 * 4);
  uint32* vhbf0  = (uint32*)alloc((size_t)NA * 64 * 4);  // [n][32][2] uints
  uint32* vhbf1  = (uint32*)alloc((size_t)NA * 64 * 4);
  int* count     = (int*)alloc((size_t)NA * 4);
  int* offsets   = (int*)alloc((size_t)(NA + 1) * 4);
  int* cursor    = (int*)alloc((size_t)NA * 4);
  int* sorted    = (int*)alloc((size_t)ET * 4);
  uint32* rec4   = (uint32*)alloc((size_t)ET * 16);
  uint32* T0     = (uint32*)alloc((size_t)T0U * 4);
  uint32* TL     = (uint32*)alloc((size_t)2 * TLU * 4);
  float* shb[2]  = {sh0, sh1};
  ushort16* shbf[2] = {shbf0, shbf1};
  float* vhb[2]  = {vh0, vh1};
  uint32* vhbf[2]= {vhbf0, vhbf1};

  // CSR build + records + tables
  hipMemsetAsync(count, 0, (size_t)NA * 4, stream);
  k_hist<<<ET / 256, 256, 0, stream>>>(rad, bon, count);
  k_scan<<<1, 256, 0, stream>>>(count, offsets, cursor);
  k_fill_embed<<<ET / 256 + NA * 64 / 256, 256, 0, stream>>>(
      rad, bon, cursor, sorted, atom_tab, types, ns0_w, cn, s_feat, s_bf);
  k_reorder_build<<<ET / 256 + 768, 256, 0, stream>>>(
      sorted, rad, bon, pos, rec4,
      We0, We1, We_ss, We_vs, We_sv, We_vv, We_vx, bond_tab, T0, TL);

  k_agg0<<<NA / 4, 256, 0, stream>>>(offsets, rec4, T0, s_bf, a_s, a_v);
  k_init_s<<<NA / 8, 256, 0, stream>>>(a_s, s_feat, Ws0, Wself0, shb[0], shbf[0]);
  k_init_v<<<NA / 8, 256, 0, stream>>>(a_v, Wv0, vhb[0], vhbf[0]);

  for (int l = 0; l < 2; ++l) {
    int bin = l & 1, bout = 1 - bin;
    k_agg_layer<<<NA / 4, 256, 0, stream>>>(
        cn, ns_w + l * 96, offsets, rec4, TL + (size_t)l * TLU, shbf[bin], vhbf[bin], a_s, a_v);
    k_mix_s<<<NA / 8, 256, 0, stream>>>(
        a_s, shb[bin], Wmix_s + l * 96 * 64, Wself_s + l * 64 * 64,
        ns_w + l * 96, skip_w + l * 192, skip_b + l * 192, cn, shb[bout], shbf[bout]);
    k_mix_v<<<NA / 8, 256, 0, stream>>>(
        a_v, vhb[bin], Wmix_v + l * 128 * 32, Wself_v + l * 32 * 32,
        ns_w + l * 96, skip_w + l * 192, skip_b + l * 192, cn, vhb[bout], vhbf[bout],
        w_out, gain, (float*)d_out, l == 1);
  }
}